// Round 5
// baseline (4235.955 us; speedup 1.0000x reference)
//
#include <hip/hip_runtime.h>
#include <math.h>

#define Bq 4
#define Tq 2048
#define Cq 1024
#define Hq 16
#define Nq 64

typedef __attribute__((ext_vector_type(8))) short short8v;
typedef __attribute__((ext_vector_type(4))) float f32x4;

__device__ inline float waveSum(float v) {
#pragma unroll
  for (int o = 32; o; o >>= 1) v += __shfl_xor(v, o);
  return v;
}
__device__ inline float sum16(float v) {
  v += __shfl_xor(v, 1);
  v += __shfl_xor(v, 2);
  v += __shfl_xor(v, 4);
  v += __shfl_xor(v, 8);
  return v;
}
__device__ inline unsigned short f2bf(float f) {
  unsigned u = __float_as_uint(f);
  unsigned r = (u + 0x7FFFu + ((u >> 16) & 1u)) >> 16;
  return (unsigned short)r;
}

__global__ __launch_bounds__(256) void f32_to_bf16_kernel(
    const float* __restrict__ src, unsigned short* __restrict__ dst, int n4)
{
  int i = blockIdx.x * 256 + threadIdx.x;
  if (i >= n4) return;
  float4 v = ((const float4*)src)[i];
  ushort4 o;
  o.x = f2bf(v.x); o.y = f2bf(v.y); o.z = f2bf(v.z); o.w = f2bf(v.w);
  ((ushort4*)dst)[i] = o;
}

// ---- f32 GEMM (K path only; precision-critical for argmax) ----
__global__ __launch_bounds__(256) void gemm_nt(
    const float* __restrict__ A, const float* __restrict__ W,
    float* __restrict__ dst, const float* __restrict__ extra,
    const float* __restrict__ lamb_p, int mode)
{
  const int K = Cq;
  const int m0 = blockIdx.x * 64, j0 = blockIdx.y * 64;
  __shared__ float As[16][65];
  __shared__ float Bs[16][65];
  const int tid = threadIdx.x;
  const int tx = tid & 15, ty = tid >> 4;
  float acc[4][4] = {{0.f}};
  for (int k0 = 0; k0 < K; k0 += 16) {
#pragma unroll
    for (int i = 0; i < 4; ++i) {
      int idx = tid + i * 256;
      int mm = idx >> 4, kk = idx & 15;
      As[kk][mm] = A[(size_t)(m0 + mm) * K + k0 + kk];
      Bs[kk][mm] = W[(size_t)(j0 + mm) * K + k0 + kk];
    }
    __syncthreads();
#pragma unroll
    for (int k = 0; k < 16; ++k) {
      float a4[4], b4[4];
#pragma unroll
      for (int i = 0; i < 4; ++i) a4[i] = As[k][ty * 4 + i];
#pragma unroll
      for (int j = 0; j < 4; ++j) b4[j] = Bs[k][tx * 4 + j];
#pragma unroll
      for (int i = 0; i < 4; ++i)
#pragma unroll
        for (int j = 0; j < 4; ++j) acc[i][j] += a4[i] * b4[j];
    }
    __syncthreads();
  }
  const float lam = (mode == 2) ? lamb_p[0] : 0.0f;
#pragma unroll
  for (int i = 0; i < 4; ++i) {
    int m = m0 + ty * 4 + i;
#pragma unroll
    for (int j = 0; j < 4; ++j) {
      int jj = j0 + tx * 4 + j;
      float v = acc[i][j];
      if (mode == 3) {
        dst[(size_t)m * Cq + jj] = v + extra[(size_t)m * Cq + jj];
      } else {
        if (mode == 2) v = (1.0f - lam) * v + lam * extra[(size_t)m * Cq + jj];
        int b = m >> 11, t = m & (Tq - 1);
        int h = jj >> 6, n = jj & 63;
        dst[((((size_t)b * Hq + h) * Tq + t) << 6) | n] = v;
      }
    }
  }
}

// ---- bf16 MFMA GEMM ----
__global__ __launch_bounds__(256) void gemm_bf16(
    const unsigned short* __restrict__ A, const unsigned short* __restrict__ W,
    float* __restrict__ dst, const float* __restrict__ extra,
    const float* __restrict__ lamb_p, int mode)
{
  const int m0 = blockIdx.x * 128, n0 = blockIdx.y * 128;
  const int tid = threadIdx.x;
  const int w = tid >> 6, l = tid & 63;
  const int wr = w >> 1, wc = w & 1;
  const int lrow = l & 15;
  const int lk = (l >> 4) * 8;

  f32x4 acc[4][4];
#pragma unroll
  for (int i = 0; i < 4; ++i)
#pragma unroll
    for (int j = 0; j < 4; ++j) acc[i][j] = (f32x4){0.f, 0.f, 0.f, 0.f};

  const unsigned short* Ab = A + (((size_t)(m0 + wr * 64 + lrow)) << 10) + lk;
  const unsigned short* Wb = W + (((size_t)(n0 + wc * 64 + lrow)) << 10) + lk;

  for (int k0 = 0; k0 < 1024; k0 += 32) {
    short8v a[4], b[4];
#pragma unroll
    for (int i = 0; i < 4; ++i) a[i] = *(const short8v*)(Ab + (((size_t)i) << 14) + k0);
#pragma unroll
    for (int j = 0; j < 4; ++j) b[j] = *(const short8v*)(Wb + (((size_t)j) << 14) + k0);
#pragma unroll
    for (int i = 0; i < 4; ++i)
#pragma unroll
      for (int j = 0; j < 4; ++j)
        acc[i][j] = __builtin_amdgcn_mfma_f32_16x16x32_bf16(a[i], b[j], acc[i][j], 0, 0, 0);
  }

  const float lam = (mode == 2) ? lamb_p[0] : 0.0f;
#pragma unroll
  for (int i = 0; i < 4; ++i)
#pragma unroll
    for (int j = 0; j < 4; ++j)
#pragma unroll
      for (int rg = 0; rg < 4; ++rg) {
        int m = m0 + wr * 64 + i * 16 + (l >> 4) * 4 + rg;
        int n = n0 + wc * 64 + j * 16 + (l & 15);
        float v = acc[i][j][rg];
        if (mode == 3) {
          dst[(size_t)m * Cq + n] = v + extra[(size_t)m * Cq + n];
        } else {
          if (mode == 2) v = (1.0f - lam) * v + lam * extra[(size_t)m * Cq + n];
          int b = m >> 11, t = m & (Tq - 1);
          int h = n >> 6, nn = n & 63;
          dst[((((size_t)b * Hq + h) * Tq + t) << 6) | nn] = v;
        }
      }
}

// LN (optional) + token-shift blend + RoPE (optional). src/dst in (B,H,T,N).
__global__ __launch_bounds__(256) void postproc(
    const float* __restrict__ src, float* __restrict__ dst,
    const float* __restrict__ lnw, const float* __restrict__ lnb,
    const float* __restrict__ xs_p, int doLNRope)
{
  const int w = threadIdx.x >> 6, lane = threadIdx.x & 63;
  const int row = blockIdx.x * 4 + w;
  const int t = row & (Tq - 1);
  const int h = (row >> 11) & (Hq - 1);
  const size_t base = (size_t)row << 6;
  const size_t pbase = (t > 0) ? base - 64 : base;
  float cur = src[base + lane];
  float prv = src[pbase + lane];
  if (doLNRope) {
    const float lw = lnw[lane], lb = lnb[lane];
    {
      float m = waveSum(cur) * (1.0f / 64.0f);
      float d = cur - m;
      float var = waveSum(d * d) * (1.0f / 64.0f);
      cur = d * rsqrtf(var + 1e-5f) * lw + lb;
    }
    {
      float m = waveSum(prv) * (1.0f / 64.0f);
      float d = prv - m;
      float var = waveSum(d * d) * (1.0f / 64.0f);
      prv = d * rsqrtf(var + 1e-5f) * lw + lb;
    }
  }
  const float xv = xs_p[h * 64 + lane];
  float val = cur + xv * (prv - cur);
  if (doLNRope) {
    float partner = __shfl_xor(val, 1);
    if (lane < 32) {
      int i = lane >> 1;
      float freq = (float)exp((double)i * (-log(10000.0) / 15.0));
      float th = (float)t * freq;
      float c = cosf(th), s = sinf(th);
      val = c * val + ((lane & 1) ? -s : s) * partner;
    }
  }
  dst[base + lane] = val;
}

__global__ __launch_bounds__(256) void kw_kernel(
    const float* __restrict__ x, const float* __restrict__ Wkw, float* __restrict__ out)
{
  const int bt = blockIdx.x;
  const int tid = threadIdx.x, w = tid >> 6, lane = tid & 63;
  __shared__ float xs[Cq];
  for (int i = tid; i < Cq; i += 256) xs[i] = x[(size_t)bt * Cq + i];
  __syncthreads();
  const int b = bt >> 11, t = bt & (Tq - 1);
  for (int h = w; h < Hq; h += 4) {
    float acc = 0.0f;
    for (int i = lane; i < Cq; i += 64) acc += xs[i] * Wkw[h * Cq + i];
    acc = waveSum(acc);
    if (lane == 0) out[((size_t)(b * Hq + h)) * Tq + t] = 1.0f / (1.0f + expf(-acc));
  }
}

// ---- state pipeline ----

__global__ __launch_bounds__(256) void zero_state_kernel(float* __restrict__ p, int n4)
{
  int i = blockIdx.x * 256 + threadIdx.x;
  if (i < n4) ((float4*)p)[i] = make_float4(0.f, 0.f, 0.f, 0.f);
}

// Precompute ck0 = LN(zero-first-32(c_k)) for chunks 0..6. Grid (64, 7) x 256.
__global__ __launch_bounds__(256) void ck0_pre_kernel(
    const float* __restrict__ kf, float* __restrict__ ck0g,
    const float* __restrict__ lnw, const float* __restrict__ lnb)
{
  const int bh = blockIdx.x, c = blockIdx.y;
  const int e = c * 256 + 256;
  const int bb = (e - 512 > 0) ? (e - 512) : 0;
  const int tid = threadIdx.x;
  const int w = tid >> 6, l = tid & 63, lr = l >> 4, lc = l & 15;
  const int d0 = lc * 4;
  const float4 lw4 = *(const float4*)(lnw + d0);
  const float4 lb4 = *(const float4*)(lnb + d0);
  const float* kb_ = kf + (size_t)bh * Tq * Nq;
  float* dst = ck0g + (((size_t)bh * 8 + c) << 14);
#pragma unroll
  for (int pass = 0; pass < 16; ++pass) {
    const int r = pass * 16 + w * 4 + lr;
    float4 kv = make_float4(0.f, 0.f, 0.f, 0.f);
    if (d0 >= 32) kv = *(const float4*)(kb_ + (size_t)(bb + r) * 64 + d0);
    float mean = sum16(kv.x + kv.y + kv.z + kv.w) * (1.0f / 64.0f);
    float dx = kv.x - mean, dy = kv.y - mean, dz = kv.z - mean, dw = kv.w - mean;
    float var = sum16(dx * dx + dy * dy + dz * dz + dw * dw) * (1.0f / 64.0f);
    float rs = rsqrtf(var + 1e-5f);
    *(float4*)(dst + r * 64 + d0) =
        make_float4(dx * rs * lw4.x + lb4.x, dy * rs * lw4.y + lb4.y,
                    dz * rs * lw4.z + lb4.z, dw * rs * lw4.w + lb4.w);
  }
}

// LN(d_k) + v_state snapshots for chunk cs. Grid 256 (4/bh) x 256.
__global__ __launch_bounds__(256) void ln_snap_kernel(
    const float* __restrict__ dkg, const float* __restrict__ dvg,
    const float* __restrict__ dcg,
    float* __restrict__ dkn_snap, float* __restrict__ vst_snap,
    const float* __restrict__ lnw, const float* __restrict__ lnb, int cs)
{
  const int bh = blockIdx.x >> 2, q = blockIdx.x & 3;
  const int tid = threadIdx.x;
  const int w = tid >> 6, l = tid & 63, lr = l >> 4, lc = l & 15;
  const int d0 = lc * 4;
  const float4 lw4 = *(const float4*)(lnw + d0);
  const float4 lb4 = *(const float4*)(lnb + d0);
  const float* dkb = dkg + (size_t)bh * 16384;
  const float* dvb = dvg + (size_t)bh * 16384;
  const float* dcb = dcg + (size_t)bh * 256;
  float* dksn = dkn_snap + (((size_t)bh * 8 + cs) << 14);
  float* vssn = vst_snap + (((size_t)bh * 8 + cs) << 14);
#pragma unroll
  for (int pass = 0; pass < 4; ++pass) {
    const int r = q * 64 + pass * 16 + w * 4 + lr;
    {
      float4 kd = *(const float4*)(dkb + r * 64 + d0);
      float mean = sum16(kd.x + kd.y + kd.z + kd.w) * (1.0f / 64.0f);
      float dx = kd.x - mean, dy = kd.y - mean, dz = kd.z - mean, dw = kd.w - mean;
      float var = sum16(dx * dx + dy * dy + dz * dz + dw * dw) * (1.0f / 64.0f);
      float rs = rsqrtf(var + 1e-5f);
      *(float4*)(dksn + r * 64 + d0) =
          make_float4(dx * rs * lw4.x + lb4.x, dy * rs * lw4.y + lb4.y,
                      dz * rs * lw4.z + lb4.z, dw * rs * lw4.w + lb4.w);
    }
    {
      float4 vd = *(const float4*)(dvb + r * 64 + d0);
      float nq = sum16(vd.x * vd.x + vd.y * vd.y + vd.z * vd.z + vd.w * vd.w);
      float nrm = fmaxf(sqrtf(nq), 1e-12f);
      float sc = dcb[r] / nrm;
      *(float4*)(vssn + r * 64 + d0) =
          make_float4(vd.x * sc, vd.y * sc, vd.z * sc, vd.w * sc);
    }
  }
}

// sim + argmax for chunk c. Grid 256 (4/bh, 64 rc each) x 512.
__global__ __launch_bounds__(512, 2) void sim_kernel(
    const float* __restrict__ ck0g, const float* __restrict__ dkn_snap,
    int* __restrict__ bestg, int c)
{
  const int bh = blockIdx.x >> 2, part = blockIdx.x & 3;
  const int tid = threadIdx.x;
  __shared__ float dknS[256 * 68];
  __shared__ float ck0S[64 * 68];

  const int w = tid >> 6, l = tid & 63, lr = l >> 4, lc = l & 15;
  const int d0 = lc * 4;
  const float* dks = dkn_snap + (((size_t)bh * 8 + c) << 14);
  const float* ckb = ck0g + (((size_t)bh * 8 + c) << 14) + (size_t)part * 64 * 64;
  // stage dkn rotated: phys(r,d) = r*68 + ((d+r)&63)
#pragma unroll
  for (int pass = 0; pass < 8; ++pass) {
    const int r = pass * 32 + w * 4 + lr;
    float4 t = *(const float4*)(dks + r * 64 + d0);
    dknS[r * 68 + ((d0 + 0 + r) & 63)] = t.x;
    dknS[r * 68 + ((d0 + 1 + r) & 63)] = t.y;
    dknS[r * 68 + ((d0 + 2 + r) & 63)] = t.z;
    dknS[r * 68 + ((d0 + 3 + r) & 63)] = t.w;
  }
#pragma unroll
  for (int pass = 0; pass < 2; ++pass) {
    const int r = pass * 32 + w * 4 + lr;
    float4 t = *(const float4*)(ckb + r * 64 + d0);
    ck0S[r * 68 + ((d0 + 0 + r) & 63)] = t.x;
    ck0S[r * 68 + ((d0 + 1 + r) & 63)] = t.y;
    ck0S[r * 68 + ((d0 + 2 + r) & 63)] = t.z;
    ck0S[r * 68 + ((d0 + 3 + r) & 63)] = t.w;
  }
  __syncthreads();

  const int tx = tid & 31, ty = tid >> 5;  // ty in [0,16): 4 rc rows each
  float acc[4][8];
#pragma unroll
  for (int i = 0; i < 4; ++i)
#pragma unroll
    for (int j = 0; j < 8; ++j) acc[i][j] = 0.0f;
#pragma unroll 2
  for (int k = 0; k < 64; ++k) {
    float av[4], bv[8];
#pragma unroll
    for (int i = 0; i < 4; ++i) {
      int r = ty * 4 + i;
      av[i] = ck0S[r * 68 + ((k + r) & 63)];
    }
#pragma unroll
    for (int j = 0; j < 8; ++j) {
      int s = tx + 32 * j;
      bv[j] = dknS[s * 68 + ((k + s) & 63)];
    }
#pragma unroll
    for (int i = 0; i < 4; ++i)
#pragma unroll
      for (int j = 0; j < 8; ++j) acc[i][j] += av[i] * bv[j];
  }
#pragma unroll
  for (int i = 0; i < 4; ++i) {
    float bvv = -3.0e38f;
    int bi = 1 << 30;
#pragma unroll
    for (int j = 0; j < 8; ++j) {
      int s = tx + 32 * j;
      float v = acc[i][j];
      if (s == 0) v = -1.0e30f;  // SINK
      if (v > bvv || (v == bvv && s < bi)) { bvv = v; bi = s; }
    }
#pragma unroll
    for (int o = 16; o; o >>= 1) {
      float ov = __shfl_xor(bvv, o);
      int oi = __shfl_xor(bi, o);
      if (ov > bvv || (ov == bvv && oi < bi)) { bvv = ov; bi = oi; }
    }
    if (tx == 0) bestg[bh * 256 + part * 64 + ty * 4 + i] = bi;
  }
}

// scatter (slot-ownership RMW) for chunk c, then LN/v_state snapshots for c+1.
// Grid 64 (1/bh) x 512.
__global__ __launch_bounds__(512, 2) void scatter_kernel(
    const float* __restrict__ ck0g, const float* __restrict__ vf,
    const float* __restrict__ kwp, const int* __restrict__ bestg,
    float* __restrict__ dkg, float* __restrict__ dvg, float* __restrict__ dcg,
    float* __restrict__ dkn_snap, float* __restrict__ vst_snap,
    const float* __restrict__ lnw, const float* __restrict__ lnb, int c)
{
  const int bh = blockIdx.x;
  const int e = c * 256 + 256;
  const int bb = (e - 512 > 0) ? (e - 512) : 0;
  const int cn = c + 1;
  const int tid = threadIdx.x;
  __shared__ int bestS[256];
  __shared__ float kwS[256];
  if (tid < 256) {
    bestS[tid] = bestg[bh * 256 + tid];
    kwS[tid] = kwp[(size_t)bh * Tq + bb + tid];
  }
  __syncthreads();

  float* dkb = dkg + (size_t)bh * 16384;
  float* dvb = dvg + (size_t)bh * 16384;
  float* dcb = dcg + (size_t)bh * 256;
  const float* ck0b = ck0g + (((size_t)bh * 8 + c) << 14);
  const float* vb_ = vf + (size_t)bh * Tq * Nq;

  {
    const int s = tid >> 1, half = tid & 1;
    const int db = half * 32;
    float accK[32], accV[32];
#pragma unroll
    for (int i = 0; i < 32; ++i) { accK[i] = 0.0f; accV[i] = 0.0f; }
    int cnt = 0;
    for (int rc = 0; rc < 256; ++rc) {
      if (bestS[rc] == s) {
        const float kwv = kwS[rc];
        const float* cr = ck0b + rc * 64 + db;
        const float* vr = vb_ + (size_t)(bb + rc) * 64 + db;
#pragma unroll
        for (int q4 = 0; q4 < 8; ++q4) {
          float4 cv = *(const float4*)(cr + q4 * 4);
          float4 vv = *(const float4*)(vr + q4 * 4);
          accK[q4 * 4 + 0] += cv.x * kwv; accK[q4 * 4 + 1] += cv.y * kwv;
          accK[q4 * 4 + 2] += cv.z * kwv; accK[q4 * 4 + 3] += cv.w * kwv;
          accV[q4 * 4 + 0] += vv.x * kwv; accV[q4 * 4 + 1] += vv.y * kwv;
          accV[q4 * 4 + 2] += vv.z * kwv; accV[q4 * 4 + 3] += vv.w * kwv;
        }
        ++cnt;
      }
    }
    if (cnt) {
      float* kp = dkb + s * 64 + db;
      float* vp = dvb + s * 64 + db;
#pragma unroll
      for (int i = 0; i < 32; ++i) { kp[i] += accK[i]; vp[i] += accV[i]; }
      if (half == 0) dcb[s] += (float)cnt;
    }
  }
  __syncthreads();

  // LN + v_state snapshots for chunk cn (reads updated global state)
  {
    const int w = tid >> 6, l = tid & 63, lr = l >> 4, lc = l & 15;
    const int d0 = lc * 4;
    const float4 lw4 = *(const float4*)(lnw + d0);
    const float4 lb4 = *(const float4*)(lnb + d0);
    float* dksn = dkn_snap + (((size_t)bh * 8 + cn) << 14);
    float* vssn = vst_snap + (((size_t)bh * 8 + cn) << 14);
#pragma unroll
    for (int pass = 0; pass < 8; ++pass) {
      const int r = pass * 32 + w * 4 + lr;
      {
        float4 kd = *(const float4*)(dkb + r * 64 + d0);
        float mean = sum16(kd.x + kd.y + kd.z + kd.w) * (1.0f / 64.0f);
        float dx = kd.x - mean, dy = kd.y - mean, dz = kd.z - mean, dw = kd.w - mean;
        float var = sum16(dx * dx + dy * dy + dz * dz + dw * dw) * (1.0f / 64.0f);
        float rs = rsqrtf(var + 1e-5f);
        *(float4*)(dksn + r * 64 + d0) =
            make_float4(dx * rs * lw4.x + lb4.x, dy * rs * lw4.y + lb4.y,
                        dz * rs * lw4.z + lb4.z, dw * rs * lw4.w + lb4.w);
      }
      {
        float4 vd = *(const float4*)(dvb + r * 64 + d0);
        float nq = sum16(vd.x * vd.x + vd.y * vd.y + vd.z * vd.z + vd.w * vd.w);
        float nrm = fmaxf(sqrtf(nq), 1e-12f);
        float sc = dcb[r] / nrm;
        *(float4*)(vssn + r * 64 + d0) =
            make_float4(vd.x * sc, vd.y * sc, vd.z * sc, vd.w * sc);
      }
    }
  }
}

// Phase B: parallel attention. Grid 512 = (bh, chunk); thread owns one q-row.
__global__ __launch_bounds__(256) void attn_apply_kernel(
    const float* __restrict__ qf, const float* __restrict__ kfin,
    const float* __restrict__ vfin, const float* __restrict__ dkn_snap,
    const float* __restrict__ vst_snap, float* __restrict__ y,
    const float* __restrict__ ftp, const float* __restrict__ stp)
{
  const int blk = blockIdx.x;
  const int bh = blk >> 3;
  const int c = blk & 7;
  const int h = bh & (Hq - 1);
  const int tid = threadIdx.x;
  const size_t seq = (size_t)Tq * Nq;
  const int qi = c * 256 + tid;
  const int e = c * 256 + 256;
  const int bb = (e - 512 > 0) ? (e - 512) : 0;
  const int L = e - bb;
  const int ntile = 4 + (L >> 6);
  const float stsc = stp[h] * 0.125f, ftsc = ftp[h] * 0.125f;

  __shared__ float Ks[4096];
  __shared__ float Vs[4096];

  float q[64], o[64];
  {
    const float* qrow = qf + (size_t)bh * seq + (size_t)qi * 64;
#pragma unroll
    for (int d4 = 0; d4 < 16; ++d4) {
      float4 t = *(const float4*)(qrow + d4 * 4);
      q[4 * d4 + 0] = t.x; q[4 * d4 + 1] = t.y;
      q[4 * d4 + 2] = t.z; q[4 * d4 + 3] = t.w;
      o[4 * d4 + 0] = 0.f; o[4 * d4 + 1] = 0.f;
      o[4 * d4 + 2] = 0.f; o[4 * d4 + 3] = 0.f;
    }
  }
  float m = -3.0e38f, l = 0.0f;

  const float* kwin = kfin + (size_t)bh * seq;
  const float* vwin = vfin + (size_t)bh * seq;
  const float* dks = dkn_snap + ((size_t)(bh * 8 + c)) * 16384;
  const float* vss = vst_snap + ((size_t)(bh * 8 + c)) * 16384;

  for (int tt = 0; tt < ntile; ++tt) {
    const float* ksrc; const float* vsrc;
    int kt0 = 0;
    if (tt < 4) {
      ksrc = dks + tt * 4096;
      vsrc = vss + tt * 4096;
    } else {
      kt0 = bb + ((tt - 4) << 6);
      ksrc = kwin + (size_t)kt0 * 64;
      vsrc = vwin + (size_t)kt0 * 64;
    }
    __syncthreads();
#pragma unroll
    for (int i = 0; i < 4; ++i) {
      ((float4*)Ks)[i * 256 + tid] = ((const float4*)ksrc)[i * 256 + tid];
      ((float4*)Vs)[i * 256 + tid] = ((const float4*)vsrc)[i * 256 + tid];
    }
    __syncthreads();
    const float scale = (tt < 4) ? stsc : ftsc;
    int jmax = 64;
    if (tt >= 4) {
      int lim = qi - kt0 + 1;
      jmax = lim < 0 ? 0 : (lim > 64 ? 64 : lim);
    }
    for (int j = 0; j < jmax; ++j) {
      const float* kr = Ks + j * 64;
      float s = 0.0f;
#pragma unroll
      for (int d4 = 0; d4 < 16; ++d4) {
        float4 kv = *(const float4*)(kr + d4 * 4);
        s += q[4 * d4 + 0] * kv.x + q[4 * d4 + 1] * kv.y +
             q[4 * d4 + 2] * kv.z + q[4 * d4 + 3] * kv.w;
      }
      s *= scale;
      const float* vr = Vs + j * 64;
      if (s > m) {
        float al = __expf(m - s);
        m = s;
        l = l * al + 1.0f;
#pragma unroll
        for (int d4 = 0; d4 < 16; ++d4) {
          float4 vv = *(const float4*)(vr + d4 * 4);
          o[4 * d4 + 0] = o[4 * d4 + 0] * al + vv.x;
          o[4 * d4 + 1] = o[4 * d4 + 1] * al + vv.y;
          o[4 * d4 + 2] = o[4 * d4 + 2] * al + vv.z;
          o[4 * d4 + 3] = o[4 * d4 + 3] * al + vv.w;
        }
      } else {
        float p = __expf(s - m);
        l += p;
#pragma unroll
        for (int d4 = 0; d4 < 16; ++d4) {
          float4 vv = *(const float4*)(vr + d4 * 4);
          o[4 * d4 + 0] += p * vv.x;
          o[4 * d4 + 1] += p * vv.y;
          o[4 * d4 + 2] += p * vv.z;
          o[4 * d4 + 3] += p * vv.w;
        }
      }
    }
  }
  const float inv = 1.0f / l;
  float* yb = y + (size_t)bh * seq + (size_t)qi * 64;
#pragma unroll
  for (int d4 = 0; d4 < 16; ++d4) {
    float4 st4 = make_float4(o[4 * d4 + 0] * inv, o[4 * d4 + 1] * inv,
                             o[4 * d4 + 2] * inv, o[4 * d4 + 3] * inv);
    *(float4*)(yb + d4 * 4) = st4;
  }
}

// LN over C=1024 per (b,t); gathers from (B,H,T,N), writes (B,T,C)
__global__ __launch_bounds__(256) void final_ln(
    const float* __restrict__ y, const float* __restrict__ lnw,
    const float* __restrict__ lnb, float* __restrict__ dst)
{
  const int bt = blockIdx.x;
  const int b = bt >> 11, t = bt & (Tq - 1);
  const int tid = threadIdx.x, w = tid >> 6, lane = tid & 63;
  __shared__ float red[8];
  float v[4];
  float s = 0.0f;
#pragma unroll
  for (int i = 0; i < 4; ++i) {
    int c = tid + (i << 8);
    int h = c >> 6, n = c & 63;
    v[i] = y[((((size_t)b * Hq + h) * Tq + t) << 6) + n];
    s += v[i];
  }
  s = waveSum(s);
  if (lane == 0) red[w] = s;
  __syncthreads();
  const float mean = (red[0] + red[1] + red[2] + red[3]) * (1.0f / 1024.0f);
  float s2 = 0.0f;
#pragma unroll
  for (int i = 0; i < 4; ++i) { float d = v[i] - mean; s2 += d * d; }
  s2 = waveSum(s2);
  if (lane == 0) red[4 + w] = s2;
  __syncthreads();
  const float var = (red[4] + red[5] + red[6] + red[7]) * (1.0f / 1024.0f);
  const float rs = rsqrtf(var + 1e-5f);
#pragma unroll
  for (int i = 0; i < 4; ++i) {
    int c = tid + (i << 8);
    dst[(size_t)bt * Cq + c] = (v[i] - mean) * rs * lnw[c] + lnb[c];
  }
}

extern "C" void kernel_launch(void* const* d_in, const int* in_sizes, int n_in,
                              void* d_out, int out_size, void* d_ws, size_t ws_size,
                              hipStream_t stream)
{
  (void)in_sizes; (void)n_in; (void)out_size; (void)ws_size;
  const float* residual = (const float*)d_in[0];
  const float* x        = (const float*)d_in[1];
  const float* v1       = (const float*)d_in[2];
  const float* Wq       = (const float*)d_in[6];
  const float* Wk       = (const float*)d_in[7];
  const float* Wv       = (const float*)d_in[8];
  const float* Wproj    = (const float*)d_in[9];
  const float* Wkw      = (const float*)d_in[10];
  const float* x_q      = (const float*)d_in[11];
  const float* x_k      = (const float*)d_in[12];
  const float* x_v      = (const float*)d_in[13];
  const float* lamb     = (const float*)d_in[14];
  const float* ln_q_w   = (const float*)d_in[15];
  const float* ln_q_b   = (const float*)d_in[16];
  const float* ln_k_w   = (const float*)d_in[17];
  const float* ln_k_b   = (const float*)d_in[18];
  const float* ln_dk_w  = (const float*)d_in[19];
  const float* ln_dk_b  = (const float*)d_in[20];
  const float* ln_res_w = (const float*)d_in[21];
  const float* ln_res_b = (const float*)d_in[22];
  const float* ftp      = (const float*)d_in[23];
  const float* stp      = (const float*)d_in[24];

  float* ws = (float*)d_ws;
  const size_t SZ = (size_t)Bq * Hq * Tq * Nq;  // 8388608
  float* q_raw = ws;
  float* k_raw = ws + SZ;
  float* v_mix = ws + 2 * SZ;
  float* q_fin = ws + 3 * SZ;
  float* k_fin = ws + 4 * SZ;
  float* v_fin = ws + 5 * SZ;
  float* kwbuf = ws + 6 * SZ;                       // B*H*T = 131072
  float* dk = kwbuf + (size_t)Bq * Hq * Tq;         // 64*16384  (dk,dv,dc contiguous)
  float* dv = dk + (size_t)Bq * Hq * 256 * 64;
  float* dc = dv + (size_t)Bq * Hq * 256 * 64;      // 64*256
  int*   bestg = (int*)(dc + (size_t)Bq * Hq * 256);
  // aliases (lifetime-disjoint):
  float* dkn_snap = q_raw;                // after q_raw dead (post postproc-q)
  float* vst_snap = k_raw;                // after k_raw dead
  float* ck0g = v_mix;                    // after v_mix dead; dead before attn writes ybuf
  float* ybuf = v_mix;
  float* ylnb = q_raw;                    // dkn_snap dead after attn_apply
  unsigned short* xb  = (unsigned short*)q_fin;
  unsigned short* wqb = xb + SZ;
  unsigned short* wvb = wqb + (1u << 20);
  unsigned short* wpb = (unsigned short*)k_fin;     // after attn_apply
  unsigned short* ylnbb = (unsigned short*)v_fin;   // after attn_apply

  dim3 gb(256);
  dim3 ggf(128, 16);
  dim3 ggb(64, 8);

  hipLaunchKernelGGL(f32_to_bf16_kernel, dim3((int)(SZ / 4 / 256)), gb, 0, stream, x, xb, (int)(SZ / 4));
  hipLaunchKernelGGL(f32_to_bf16_kernel, dim3(1024), gb, 0, stream, Wq, wqb, 262144);
  hipLaunchKernelGGL(f32_to_bf16_kernel, dim3(1024), gb, 0, stream, Wv, wvb, 262144);

  hipLaunchKernelGGL(gemm_bf16, ggb, gb, 0, stream, xb, wqb, q_raw, (const float*)nullptr, lamb, 1);
  hipLaunchKernelGGL(gemm_nt, ggf, gb, 0, stream, x, Wk, k_raw, (const float*)nullptr, lamb, 1);
  hipLaunchKernelGGL(gemm_bf16, ggb, gb, 0, stream, xb, wvb, v_mix, v1, lamb, 2);
  hipLaunchKernelGGL(kw_kernel, dim3(Bq * Tq), gb, 0, stream, x, Wkw, kwbuf);

  const int rows = Bq * Hq * Tq;
  hipLaunchKernelGGL(postproc, dim3(rows / 4), gb, 0, stream, q_raw, q_fin, ln_q_w, ln_q_b, x_q, 1);
  hipLaunchKernelGGL(postproc, dim3(rows / 4), gb, 0, stream, k_raw, k_fin, ln_k_w, ln_k_b, x_k, 1);
  hipLaunchKernelGGL(postproc, dim3(rows / 4), gb, 0, stream, v_mix, v_fin, (const float*)nullptr, (const float*)nullptr, x_v, 0);

  // state pipeline
  const int zero_n4 = (int)((2 * (size_t)Bq * Hq * 256 * 64 + (size_t)Bq * Hq * 256) / 4);
  hipLaunchKernelGGL(zero_state_kernel, dim3((zero_n4 + 255) / 256), gb, 0, stream, dk, zero_n4);
  hipLaunchKernelGGL(ck0_pre_kernel, dim3(Bq * Hq, 7), gb, 0, stream, k_fin, ck0g, ln_dk_w, ln_dk_b);
  hipLaunchKernelGGL(ln_snap_kernel, dim3(Bq * Hq * 4), gb, 0, stream, dk, dv, dc,
                     dkn_snap, vst_snap, ln_dk_w, ln_dk_b, 0);
  for (int c = 0; c < 7; ++c) {
    hipLaunchKernelGGL(sim_kernel, dim3(Bq * Hq * 4), dim3(512), 0, stream,
                       ck0g, dkn_snap, bestg, c);
    hipLaunchKernelGGL(scatter_kernel, dim3(Bq * Hq), dim3(512), 0, stream,
                       ck0g, v_fin, kwbuf, bestg, dk, dv, dc,
                       dkn_snap, vst_snap, ln_dk_w, ln_dk_b, c);
  }

  hipLaunchKernelGGL(attn_apply_kernel, dim3(Bq * Hq * 8), gb, 0, stream,
                     q_fin, k_fin, v_fin, dkn_snap, vst_snap, ybuf, ftp, stp);

  hipLaunchKernelGGL(f32_to_bf16_kernel, dim3(1024), gb, 0, stream, Wproj, wpb, 262144);
  hipLaunchKernelGGL(final_ln, dim3(Bq * Tq), gb, 0, stream, ybuf, ln_res_w, ln_res_b, ylnb);
  hipLaunchKernelGGL(f32_to_bf16_kernel, dim3((int)(SZ / 4 / 256)), gb, 0, stream, ylnb, ylnbb, (int)(SZ / 4));
  hipLaunchKernelGGL(gemm_bf16, ggb, gb, 0, stream, ylnbb, wpb, (float*)d_out, residual, lamb, 3);
}

// Round 6
// 2255.511 us; speedup vs baseline: 1.8780x; 1.8780x over previous
//
#include <hip/hip_runtime.h>
#include <math.h>

#define Bq 4
#define Tq 2048
#define Cq 1024
#define Hq 16
#define Nq 64

typedef __attribute__((ext_vector_type(8))) short short8v;
typedef __attribute__((ext_vector_type(4))) float f32x4;

__device__ inline float waveSum(float v) {
#pragma unroll
  for (int o = 32; o; o >>= 1) v += __shfl_xor(v, o);
  return v;
}
__device__ inline unsigned short f2bf(float f) {
  unsigned u = __float_as_uint(f);
  unsigned r = (u + 0x7FFFu + ((u >> 16) & 1u)) >> 16;
  return (unsigned short)r;
}
__device__ inline float bf2f(unsigned short b) {
  return __uint_as_float(((unsigned)b) << 16);
}

__global__ __launch_bounds__(256) void f32_to_bf16_kernel(
    const float* __restrict__ src, unsigned short* __restrict__ dst, int n4)
{
  int i = blockIdx.x * 256 + threadIdx.x;
  if (i >= n4) return;
  float4 v = ((const float4*)src)[i];
  ushort4 o;
  o.x = f2bf(v.x); o.y = f2bf(v.y); o.z = f2bf(v.z); o.w = f2bf(v.w);
  ((ushort4*)dst)[i] = o;
}

// ---- f32 GEMM (K path only; precision-critical for argmax) ----
__global__ __launch_bounds__(256) void gemm_nt(
    const float* __restrict__ A, const float* __restrict__ W,
    float* __restrict__ dst, const float* __restrict__ extra,
    const float* __restrict__ lamb_p, int mode)
{
  const int K = Cq;
  const int m0 = blockIdx.x * 64, j0 = blockIdx.y * 64;
  __shared__ float As[16][65];
  __shared__ float Bs[16][65];
  const int tid = threadIdx.x;
  const int tx = tid & 15, ty = tid >> 4;
  float acc[4][4] = {{0.f}};
  for (int k0 = 0; k0 < K; k0 += 16) {
#pragma unroll
    for (int i = 0; i < 4; ++i) {
      int idx = tid + i * 256;
      int mm = idx >> 4, kk = idx & 15;
      As[kk][mm] = A[(size_t)(m0 + mm) * K + k0 + kk];
      Bs[kk][mm] = W[(size_t)(j0 + mm) * K + k0 + kk];
    }
    __syncthreads();
#pragma unroll
    for (int k = 0; k < 16; ++k) {
      float a4[4], b4[4];
#pragma unroll
      for (int i = 0; i < 4; ++i) a4[i] = As[k][ty * 4 + i];
#pragma unroll
      for (int j = 0; j < 4; ++j) b4[j] = Bs[k][tx * 4 + j];
#pragma unroll
      for (int i = 0; i < 4; ++i)
#pragma unroll
        for (int j = 0; j < 4; ++j) acc[i][j] += a4[i] * b4[j];
    }
    __syncthreads();
  }
#pragma unroll
  for (int i = 0; i < 4; ++i) {
    int m = m0 + ty * 4 + i;
#pragma unroll
    for (int j = 0; j < 4; ++j) {
      int jj = j0 + tx * 4 + j;
      float v = acc[i][j];
      int b = m >> 11, t = m & (Tq - 1);
      int h = jj >> 6, n = jj & 63;
      dst[((((size_t)b * Hq + h) * Tq + t) << 6) | n] = v;
    }
  }
  (void)extra; (void)lamb_p; (void)mode;
}

// ---- bf16 MFMA GEMM ----
__global__ __launch_bounds__(256) void gemm_bf16(
    const unsigned short* __restrict__ A, const unsigned short* __restrict__ W,
    float* __restrict__ dst, const float* __restrict__ extra,
    const float* __restrict__ lamb_p, int mode)
{
  const int m0 = blockIdx.x * 128, n0 = blockIdx.y * 128;
  const int tid = threadIdx.x;
  const int w = tid >> 6, l = tid & 63;
  const int wr = w >> 1, wc = w & 1;
  const int lrow = l & 15;
  const int lk = (l >> 4) * 8;

  f32x4 acc[4][4];
#pragma unroll
  for (int i = 0; i < 4; ++i)
#pragma unroll
    for (int j = 0; j < 4; ++j) acc[i][j] = (f32x4){0.f, 0.f, 0.f, 0.f};

  const unsigned short* Ab = A + (((size_t)(m0 + wr * 64 + lrow)) << 10) + lk;
  const unsigned short* Wb = W + (((size_t)(n0 + wc * 64 + lrow)) << 10) + lk;

  for (int k0 = 0; k0 < 1024; k0 += 32) {
    short8v a[4], b[4];
#pragma unroll
    for (int i = 0; i < 4; ++i) a[i] = *(const short8v*)(Ab + (((size_t)i) << 14) + k0);
#pragma unroll
    for (int j = 0; j < 4; ++j) b[j] = *(const short8v*)(Wb + (((size_t)j) << 14) + k0);
#pragma unroll
    for (int i = 0; i < 4; ++i)
#pragma unroll
      for (int j = 0; j < 4; ++j)
        acc[i][j] = __builtin_amdgcn_mfma_f32_16x16x32_bf16(a[i], b[j], acc[i][j], 0, 0, 0);
  }

  const float lam = (mode == 2) ? lamb_p[0] : 0.0f;
#pragma unroll
  for (int i = 0; i < 4; ++i)
#pragma unroll
    for (int j = 0; j < 4; ++j)
#pragma unroll
      for (int rg = 0; rg < 4; ++rg) {
        int m = m0 + wr * 64 + i * 16 + (l >> 4) * 4 + rg;
        int n = n0 + wc * 64 + j * 16 + (l & 15);
        float v = acc[i][j][rg];
        if (mode == 3) {
          dst[(size_t)m * Cq + n] = v + extra[(size_t)m * Cq + n];
        } else {
          if (mode == 2) v = (1.0f - lam) * v + lam * extra[(size_t)m * Cq + n];
          int b = m >> 11, t = m & (Tq - 1);
          int h = n >> 6, nn = n & 63;
          dst[((((size_t)b * Hq + h) * Tq + t) << 6) | nn] = v;
        }
      }
}

// LN (optional) + token-shift + RoPE (optional). src in (B,H,T,N).
// Writes f32 (if dst) and/or bf16 (if dst_bf).
__global__ __launch_bounds__(256) void postproc(
    const float* __restrict__ src, float* __restrict__ dst,
    unsigned short* __restrict__ dst_bf,
    const float* __restrict__ lnw, const float* __restrict__ lnb,
    const float* __restrict__ xs_p, int doLNRope)
{
  const int w = threadIdx.x >> 6, lane = threadIdx.x & 63;
  const int row = blockIdx.x * 4 + w;
  const int t = row & (Tq - 1);
  const int h = (row >> 11) & (Hq - 1);
  const size_t base = (size_t)row << 6;
  const size_t pbase = (t > 0) ? base - 64 : base;
  float cur = src[base + lane];
  float prv = src[pbase + lane];
  if (doLNRope) {
    const float lw = lnw[lane], lb = lnb[lane];
    {
      float m = waveSum(cur) * (1.0f / 64.0f);
      float d = cur - m;
      float var = waveSum(d * d) * (1.0f / 64.0f);
      cur = d * rsqrtf(var + 1e-5f) * lw + lb;
    }
    {
      float m = waveSum(prv) * (1.0f / 64.0f);
      float d = prv - m;
      float var = waveSum(d * d) * (1.0f / 64.0f);
      prv = d * rsqrtf(var + 1e-5f) * lw + lb;
    }
  }
  const float xv = xs_p[h * 64 + lane];
  float val = cur + xv * (prv - cur);
  if (doLNRope) {
    float partner = __shfl_xor(val, 1);
    if (lane < 32) {
      int i = lane >> 1;
      float freq = (float)exp((double)i * (-log(10000.0) / 15.0));
      float th = (float)t * freq;
      float c = cosf(th), s = sinf(th);
      val = c * val + ((lane & 1) ? -s : s) * partner;
    }
  }
  if (dst) dst[base + lane] = val;
  if (dst_bf) dst_bf[base + lane] = f2bf(val);
}

__global__ __launch_bounds__(256) void kw_kernel(
    const float* __restrict__ x, const float* __restrict__ Wkw, float* __restrict__ out)
{
  const int bt = blockIdx.x;
  const int tid = threadIdx.x, w = tid >> 6, lane = tid & 63;
  __shared__ float xs[Cq];
  for (int i = tid; i < Cq; i += 256) xs[i] = x[(size_t)bt * Cq + i];
  __syncthreads();
  const int b = bt >> 11, t = bt & (Tq - 1);
  for (int h = w; h < Hq; h += 4) {
    float acc = 0.0f;
    for (int i = lane; i < Cq; i += 64) acc += xs[i] * Wkw[h * Cq + i];
    acc = waveSum(acc);
    if (lane == 0) out[((size_t)(b * Hq + h)) * Tq + t] = 1.0f / (1.0f + expf(-acc));
  }
}

// Phase A: state evolution, 64 blocks x 1024 threads.
// d_k/d_v/cnt live in REGISTERS (thread = slot s, quarter qd). Snapshots bf16.
__global__ __launch_bounds__(1024, 4) void state_evolve_kernel(
    const float* __restrict__ kf, const unsigned short* __restrict__ v_bf,
    const float* __restrict__ kwp,
    unsigned short* __restrict__ dkn_bf, unsigned short* __restrict__ vst_bf,
    float* __restrict__ cnt_snap,
    const float* __restrict__ lnw, const float* __restrict__ lnb)
{
  const int bh = blockIdx.x;
  const int tid = threadIdx.x;
  const int s = tid >> 2, qd = tid & 3;
  const int db = qd * 16;
  const size_t seq = (size_t)Tq * Nq;
  const float* kb_ = kf + (size_t)bh * seq;
  const unsigned short* vb_ = v_bf + (size_t)bh * seq;
  const float* kwb = kwp + (size_t)bh * Tq;

  __shared__ float dknR[256 * 68];  // rotated; reused for V window (plain) in scatter
  __shared__ float ck0R[256 * 68];  // rotated
  __shared__ float kwc_s[256];
  __shared__ int best_s[256];

  float dkReg[16], dvReg[16];
#pragma unroll
  for (int i = 0; i < 16; ++i) { dkReg[i] = 0.f; dvReg[i] = 0.f; }
  float cnt = 0.f;

  for (int c = 0; c < 8; ++c) {
    const int e = c * 256 + 256;
    const int bb = (e - 512 > 0) ? (e - 512) : 0;

    // ---- phase A: LN(d_k) -> dknR + bf16 snapshot; unit v_state -> bf16 snapshot; cnt
    {
      float sum = 0.f;
#pragma unroll
      for (int i = 0; i < 16; ++i) sum += dkReg[i];
      sum += __shfl_xor(sum, 1); sum += __shfl_xor(sum, 2);
      const float mean = sum * (1.0f / 64.0f);
      float sq = 0.f;
#pragma unroll
      for (int i = 0; i < 16; ++i) { float d = dkReg[i] - mean; sq += d * d; }
      sq += __shfl_xor(sq, 1); sq += __shfl_xor(sq, 2);
      const float rs = rsqrtf(sq * (1.0f / 64.0f) + 1e-5f);
      float kn[16];
#pragma unroll
      for (int i = 0; i < 16; ++i)
        kn[i] = (dkReg[i] - mean) * rs * lnw[db + i] + lnb[db + i];
      if (c < 7) {
#pragma unroll
        for (int i = 0; i < 16; ++i) dknR[s * 68 + ((db + i + s) & 63)] = kn[i];
      }
      unsigned int pk[8];
#pragma unroll
      for (int i2 = 0; i2 < 8; ++i2)
        pk[i2] = (unsigned)f2bf(kn[2 * i2]) | ((unsigned)f2bf(kn[2 * i2 + 1]) << 16);
      unsigned short* kd = dkn_bf + (((size_t)bh * 8 + c) << 14) + s * 64 + db;
      *(uint4*)kd = make_uint4(pk[0], pk[1], pk[2], pk[3]);
      *(uint4*)(kd + 8) = make_uint4(pk[4], pk[5], pk[6], pk[7]);

      float sqv = 0.f;
#pragma unroll
      for (int i = 0; i < 16; ++i) sqv += dvReg[i] * dvReg[i];
      sqv += __shfl_xor(sqv, 1); sqv += __shfl_xor(sqv, 2);
      const float inrm = 1.0f / fmaxf(sqrtf(sqv), 1e-12f);
#pragma unroll
      for (int i2 = 0; i2 < 8; ++i2)
        pk[i2] = (unsigned)f2bf(dvReg[2 * i2] * inrm) |
                 ((unsigned)f2bf(dvReg[2 * i2 + 1] * inrm) << 16);
      unsigned short* vd = vst_bf + (((size_t)bh * 8 + c) << 14) + s * 64 + db;
      *(uint4*)vd = make_uint4(pk[0], pk[1], pk[2], pk[3]);
      *(uint4*)(vd + 8) = make_uint4(pk[4], pk[5], pk[6], pk[7]);
      if (qd == 0) cnt_snap[((size_t)bh * 8 + c) * 256 + s] = cnt;
    }

    if (c < 7) {
      // ---- phase B: ck0 = LN(zero-first-32(k window)) -> ck0R (rotated)
      {
        const int r = s;
        float kv[16];
        if (qd >= 2) {
          const float* krow = kb_ + (size_t)(bb + r) * 64 + db;
#pragma unroll
          for (int i = 0; i < 16; i += 4) {
            float4 t4 = *(const float4*)(krow + i);
            kv[i] = t4.x; kv[i + 1] = t4.y; kv[i + 2] = t4.z; kv[i + 3] = t4.w;
          }
        } else {
#pragma unroll
          for (int i = 0; i < 16; ++i) kv[i] = 0.f;
        }
        float sum = 0.f;
#pragma unroll
        for (int i = 0; i < 16; ++i) sum += kv[i];
        sum += __shfl_xor(sum, 1); sum += __shfl_xor(sum, 2);
        const float mean = sum * (1.0f / 64.0f);
        float sq = 0.f;
#pragma unroll
        for (int i = 0; i < 16; ++i) { float d = kv[i] - mean; sq += d * d; }
        sq += __shfl_xor(sq, 1); sq += __shfl_xor(sq, 2);
        const float rs = rsqrtf(sq * (1.0f / 64.0f) + 1e-5f);
#pragma unroll
        for (int i = 0; i < 16; ++i)
          ck0R[r * 68 + ((db + i + r) & 63)] =
              (kv[i] - mean) * rs * lnw[db + i] + lnb[db + i];
        if (qd == 0) kwc_s[r] = kwb[bb + r];
      }
      __syncthreads();

      // ---- phase C: sim (2 passes of acc[4][8], no spill) + fused argmax
      {
        const int ty = tid >> 5, tx = tid & 31;
#pragma unroll
        for (int pass = 0; pass < 2; ++pass) {
          const int rc0 = pass * 128 + ty * 4;
          float acc[4][8];
#pragma unroll
          for (int i = 0; i < 4; ++i)
#pragma unroll
            for (int j = 0; j < 8; ++j) acc[i][j] = 0.f;
          for (int k = 0; k < 64; ++k) {
            float av[4], bv[8];
#pragma unroll
            for (int i = 0; i < 4; ++i)
              av[i] = ck0R[(rc0 + i) * 68 + ((k + rc0 + i) & 63)];
#pragma unroll
            for (int j = 0; j < 8; ++j) {
              int s2 = tx + 32 * j;
              bv[j] = dknR[s2 * 68 + ((k + s2) & 63)];
            }
#pragma unroll
            for (int i = 0; i < 4; ++i)
#pragma unroll
              for (int j = 0; j < 8; ++j) acc[i][j] += av[i] * bv[j];
          }
#pragma unroll
          for (int i = 0; i < 4; ++i) {
            float bvv = -3.0e38f;
            int bi = 1 << 30;
#pragma unroll
            for (int j = 0; j < 8; ++j) {
              int s2 = tx + 32 * j;
              float v = acc[i][j];
              if (s2 == 0) v = -1.0e30f;  // SINK
              if (v > bvv || (v == bvv && s2 < bi)) { bvv = v; bi = s2; }
            }
#pragma unroll
            for (int o = 16; o; o >>= 1) {
              float ov = __shfl_xor(bvv, o);
              int oi = __shfl_xor(bi, o);
              if (ov > bvv || (ov == bvv && oi < bi)) { bvv = ov; bi = oi; }
            }
            if (tx == 0) best_s[rc0 + i] = bi;
          }
        }
      }
      __syncthreads();

      // ---- phase D: stage V window (bf16->f32) into dknR (plain), scatter to regs
#pragma unroll
      for (int it = 0; it < 4; ++it) {
        const int r = it * 64 + (tid >> 4);
        const int c4 = (tid & 15) * 4;
        const unsigned short* vrow = vb_ + (size_t)(bb + r) * 64 + c4;
        uint2 u = *(const uint2*)vrow;
        float4 f;
        f.x = __uint_as_float((u.x & 0xFFFFu) << 16);
        f.y = __uint_as_float(u.x & 0xFFFF0000u);
        f.z = __uint_as_float((u.y & 0xFFFFu) << 16);
        f.w = __uint_as_float(u.y & 0xFFFF0000u);
        *(float4*)&dknR[r * 68 + c4] = f;
      }
      __syncthreads();
      {
        int cadd = 0;
        for (int rc = 0; rc < 256; ++rc) {
          if (best_s[rc] == s) {
            const float kwv = kwc_s[rc];
#pragma unroll
            for (int i = 0; i < 16; ++i) {
              dkReg[i] += ck0R[rc * 68 + ((db + i + rc) & 63)] * kwv;
              dvReg[i] += dknR[rc * 68 + db + i] * kwv;
            }
            ++cadd;
          }
        }
        cnt += (float)cadd;
      }
      __syncthreads();
    }
  }
}

// Phase B: MFMA flash attention. Grid 1024 = (bh, c, half); 256 thr, 4 waves x 32 rows.
__global__ __launch_bounds__(256, 2) void attn_mfma_kernel(
    const unsigned short* __restrict__ q_bf, const unsigned short* __restrict__ k_bf,
    const unsigned short* __restrict__ v_bf,
    const unsigned short* __restrict__ dkn_bf, const unsigned short* __restrict__ vst_bf,
    const float* __restrict__ cnt_snap, float* __restrict__ y,
    const float* __restrict__ ftp, const float* __restrict__ stp)
{
  const int blk = blockIdx.x;
  const int bh = blk >> 4;
  const int c = (blk >> 1) & 7;
  const int half = blk & 1;
  const int h = bh & (Hq - 1);
  const int tid = threadIdx.x;
  const int w = tid >> 6, l = tid & 63;
  const int g = l >> 4, n = l & 15;
  const int rows0 = c * 256 + half * 128 + w * 32;
  const int e = c * 256 + 256;
  const int bb = (e - 512 > 0) ? (e - 512) : 0;
  const int nwt = (e - bb) >> 6;  // 4 or 8
  const float stsc = stp[h] * 0.125f, ftsc = ftp[h] * 0.125f;
  const size_t seq = (size_t)Tq * Nq;

  __shared__ unsigned short Ks[64 * 72];
  __shared__ unsigned short VTs[64 * 72];
  __shared__ unsigned short Ps[4][32 * 72];
  __shared__ float wts[64];

  // Q fragments (A operand): row = l&15, k = kh*32 + g*8
  short8v qf[2][2];
#pragma unroll
  for (int mt = 0; mt < 2; ++mt)
#pragma unroll
    for (int kh = 0; kh < 2; ++kh)
      qf[mt][kh] = *(const short8v*)(q_bf + (size_t)bh * seq +
                                     (size_t)(rows0 + mt * 16 + n) * 64 + kh * 32 + g * 8);

  f32x4 oacc[2][4];
#pragma unroll
  for (int mt = 0; mt < 2; ++mt)
#pragma unroll
    for (int dt = 0; dt < 4; ++dt) oacc[mt][dt] = (f32x4){0.f, 0.f, 0.f, 0.f};
  float rowM[2][4], rowL[2][4];
#pragma unroll
  for (int mt = 0; mt < 2; ++mt)
#pragma unroll
    for (int r = 0; r < 4; ++r) { rowM[mt][r] = -1.0e30f; rowL[mt][r] = 0.f; }

  const int nkt = 4 + nwt;
  for (int kt = 0; kt < nkt; ++kt) {
    const bool isState = kt < 4;
    const int t0 = isState ? kt * 64 : bb + (kt - 4) * 64;
    const unsigned short* ksrc = isState
        ? dkn_bf + (((size_t)bh * 8 + c) << 14) + (size_t)t0 * 64
        : k_bf + (size_t)bh * seq + (size_t)t0 * 64;
    const unsigned short* vsrc = isState
        ? vst_bf + (((size_t)bh * 8 + c) << 14) + (size_t)t0 * 64
        : v_bf + (size_t)bh * seq + (size_t)t0 * 64;

    __syncthreads();
    {
      const int row = tid >> 2, q4 = tid & 3;
      const unsigned short* src = ksrc + row * 64 + q4 * 16;
      *(uint4*)&Ks[row * 72 + q4 * 16] = *(const uint4*)src;
      *(uint4*)&Ks[row * 72 + q4 * 16 + 8] = *(const uint4*)(src + 8);
      const unsigned short* vs = vsrc + row * 64 + q4 * 16;
#pragma unroll
      for (int i = 0; i < 16; ++i) VTs[(q4 * 16 + i) * 72 + row] = vs[i];
      if (tid < 64)
        wts[tid] = isState ? cnt_snap[((size_t)bh * 8 + c) * 256 + kt * 64 + tid] : 1.0f;
    }
    __syncthreads();

    // S = Q . K^T
    f32x4 sacc[2][4];
#pragma unroll
    for (int mt = 0; mt < 2; ++mt)
#pragma unroll
      for (int nt = 0; nt < 4; ++nt) sacc[mt][nt] = (f32x4){0.f, 0.f, 0.f, 0.f};
#pragma unroll
    for (int nt = 0; nt < 4; ++nt) {
      short8v kf0 = *(const short8v*)&Ks[(nt * 16 + n) * 72 + g * 8];
      short8v kf1 = *(const short8v*)&Ks[(nt * 16 + n) * 72 + 32 + g * 8];
#pragma unroll
      for (int mt = 0; mt < 2; ++mt) {
        sacc[mt][nt] = __builtin_amdgcn_mfma_f32_16x16x32_bf16(qf[mt][0], kf0, sacc[mt][nt], 0, 0, 0);
        sacc[mt][nt] = __builtin_amdgcn_mfma_f32_16x16x32_bf16(qf[mt][1], kf1, sacc[mt][nt], 0, 0, 0);
      }
    }

    const float scale = isState ? stsc : ftsc;
    float wt_n[4];
#pragma unroll
    for (int nt = 0; nt < 4; ++nt) wt_n[nt] = wts[nt * 16 + n];

#pragma unroll
    for (int mt = 0; mt < 2; ++mt) {
#pragma unroll
      for (int r = 0; r < 4; ++r) {
        float sv[4];
#pragma unroll
        for (int nt = 0; nt < 4; ++nt) {
          float s = sacc[mt][nt][r] * scale;
          if (!isState) {
            int qi = rows0 + mt * 16 + g * 4 + r;
            int kj = t0 + nt * 16 + n;
            if (kj > qi) s = -1.0e30f;
          }
          sv[nt] = s;
        }
        float tmax = fmaxf(fmaxf(sv[0], sv[1]), fmaxf(sv[2], sv[3]));
        tmax = fmaxf(tmax, __shfl_xor(tmax, 1));
        tmax = fmaxf(tmax, __shfl_xor(tmax, 2));
        tmax = fmaxf(tmax, __shfl_xor(tmax, 4));
        tmax = fmaxf(tmax, __shfl_xor(tmax, 8));
        const float Mold = rowM[mt][r];
        const float Mnew = fmaxf(Mold, tmax);
        const float al = __expf(Mold - Mnew);
        rowM[mt][r] = Mnew;
        float p[4], ts = 0.f;
#pragma unroll
        for (int nt = 0; nt < 4; ++nt) { p[nt] = __expf(sv[nt] - Mnew); ts += p[nt]; }
        ts += __shfl_xor(ts, 1);
        ts += __shfl_xor(ts, 2);
        ts += __shfl_xor(ts, 4);
        ts += __shfl_xor(ts, 8);
        rowL[mt][r] = rowL[mt][r] * al + ts;
#pragma unroll
        for (int dt = 0; dt < 4; ++dt) oacc[mt][dt][r] *= al;
        const int prow = (mt * 16 + g * 4 + r) * 72;
#pragma unroll
        for (int nt = 0; nt < 4; ++nt)
          Ps[w][prow + nt * 16 + n] = f2bf(p[nt] * wt_n[nt]);
      }
    }

    // O += P . V  (A = P[m][j], B = VT[d][j])
    short8v pf[2][2];
#pragma unroll
    for (int mt = 0; mt < 2; ++mt)
#pragma unroll
      for (int jh = 0; jh < 2; ++jh)
        pf[mt][jh] = *(const short8v*)&Ps[w][(mt * 16 + n) * 72 + jh * 32 + g * 8];
#pragma unroll
    for (int dt = 0; dt < 4; ++dt) {
      short8v vf0 = *(const short8v*)&VTs[(dt * 16 + n) * 72 + g * 8];
      short8v vf1 = *(const short8v*)&VTs[(dt * 16 + n) * 72 + 32 + g * 8];
#pragma unroll
      for (int mt = 0; mt < 2; ++mt) {
        oacc[mt][dt] = __builtin_amdgcn_mfma_f32_16x16x32_bf16(pf[mt][0], vf0, oacc[mt][dt], 0, 0, 0);
        oacc[mt][dt] = __builtin_amdgcn_mfma_f32_16x16x32_bf16(pf[mt][1], vf1, oacc[mt][dt], 0, 0, 0);
      }
    }
  }

  // write out: y[row][d] = oacc / rowL
#pragma unroll
  for (int mt = 0; mt < 2; ++mt) {
#pragma unroll
    for (int r = 0; r < 4; ++r) {
      const float inv = 1.0f / rowL[mt][r];
      const int row = rows0 + mt * 16 + g * 4 + r;
#pragma unroll
      for (int dt = 0; dt < 4; ++dt)
        y[(size_t)bh * seq + (size_t)row * 64 + dt * 16 + n] = oacc[mt][dt][r] * inv;
    }
  }
}

// LN over C=1024 per (b,t); gathers from (B,H,T,N), writes bf16 (B,T,C)
__global__ __launch_bounds__(256) void final_ln(
    const float* __restrict__ y, const float* __restrict__ lnw,
    const float* __restrict__ lnb, unsigned short* __restrict__ dst)
{
  const int bt = blockIdx.x;
  const int b = bt >> 11, t = bt & (Tq - 1);
  const int tid = threadIdx.x, w = tid >> 6, lane = tid & 63;
  __shared__ float red[8];
  float v[4];
  float s = 0.0f;
#pragma unroll
  for (int i = 0; i < 4; ++i) {
    int c = tid + (i << 8);
    int h = c >> 6, n = c & 63;
    v[i] = y[((((size_t)b * Hq + h) * Tq + t) << 6) + n];
    s += v[i];
  }
  s = waveSum(s);
  if (lane == 0) red[w] = s;
  __syncthreads();
  const float mean = (red[0] + red[1] + red[2] + red[3]) * (1.0f / 1024.0f);
  float s2 = 0.0f;
#pragma unroll
  for (int i = 0; i < 4; ++i) { float d = v[i] - mean; s2 += d * d; }
  s2 = waveSum(s2);
  if (lane == 0) red[4 + w] = s2;
  __syncthreads();
  const float var = (red[4] + red[5] + red[6] + red[7]) * (1.0f / 1024.0f);
  const float rs = rsqrtf(var + 1e-5f);
#pragma unroll
  for (int i = 0; i < 4; ++i) {
    int c = tid + (i << 8);
    dst[(size_t)bt * Cq + c] = f2bf((v[i] - mean) * rs * lnw[c] + lnb[c]);
  }
}

extern "C" void kernel_launch(void* const* d_in, const int* in_sizes, int n_in,
                              void* d_out, int out_size, void* d_ws, size_t ws_size,
                              hipStream_t stream)
{
  (void)in_sizes; (void)n_in; (void)out_size; (void)ws_size;
  const float* residual = (const float*)d_in[0];
  const float* x        = (const float*)d_in[1];
  const float* v1       = (const float*)d_in[2];
  const float* Wq       = (const float*)d_in[6];
  const float* Wk       = (const float*)d_in[7];
  const float* Wv       = (const float*)d_in[8];
  const float* Wproj    = (const float*)d_in[9];
  const float* Wkw      = (const float*)d_in[10];
  const float* x_q      = (const float*)d_in[11];
  const float* x_k      = (const float*)d_in[12];
  const float* x_v      = (const float*)d_in[13];
  const float* lamb     = (const float*)d_in[14];
  const float* ln_q_w   = (const float*)d_in[15];
  const float* ln_q_b   = (const float*)d_in[16];
  const float* ln_k_w   = (const float*)d_in[17];
  const float* ln_k_b   = (const float*)d_in[18];
  const float* ln_dk_w  = (const float*)d_in[19];
  const float* ln_dk_b  = (const float*)d_in[20];
  const float* ln_res_w = (const float*)d_in[21];
  const float* ln_res_b = (const float*)d_in[22];
  const float* ftp      = (const float*)d_in[23];
  const float* stp      = (const float*)d_in[24];

  float* ws = (float*)d_ws;
  const size_t SZ = (size_t)Bq * Hq * Tq * Nq;  // 8388608
  // region A: q_raw (f32 gemm out) -> ybuf (attn out)
  float* q_raw = ws;
  float* ybuf  = ws;
  // region B: k_raw -> {vst_bf, cnt_snap}
  float* k_raw = ws + SZ;
  unsigned short* vst_bf = (unsigned short*)(ws + SZ);
  float* cnt_snap = ws + SZ + SZ / 2;
  // region C: v_mix -> ylnb_bf
  float* v_mix = ws + 2 * SZ;
  unsigned short* ylnb_bf = (unsigned short*)(ws + 2 * SZ);
  // region D: k_fin (f32, state path)
  float* k_fin = ws + 3 * SZ;
  // region E: q_bf | k_bf
  unsigned short* q_bf = (unsigned short*)(ws + 4 * SZ);
  unsigned short* k_bf = q_bf + SZ;
  // region F: v_bf | xb->dkn_bf
  unsigned short* v_bf = (unsigned short*)(ws + 5 * SZ);
  unsigned short* xb   = v_bf + SZ;
  unsigned short* dkn_bf = xb;
  // region G: weights bf16 + kwbuf
  unsigned short* wqb = (unsigned short*)(ws + 6 * SZ);
  unsigned short* wvb = wqb + (1u << 20);
  unsigned short* wpb = wvb + (1u << 20);
  float* kwbuf = ws + 6 * SZ + ((3u << 20) >> 1);

  dim3 gb(256);
  dim3 ggf(128, 16);
  dim3 ggb(64, 8);

  hipLaunchKernelGGL(f32_to_bf16_kernel, dim3((int)(SZ / 4 / 256)), gb, 0, stream, x, xb, (int)(SZ / 4));
  hipLaunchKernelGGL(f32_to_bf16_kernel, dim3(1024), gb, 0, stream, Wq, wqb, 262144);
  hipLaunchKernelGGL(f32_to_bf16_kernel, dim3(1024), gb, 0, stream, Wv, wvb, 262144);
  hipLaunchKernelGGL(f32_to_bf16_kernel, dim3(1024), gb, 0, stream, Wproj, wpb, 262144);

  hipLaunchKernelGGL(gemm_bf16, ggb, gb, 0, stream, xb, wqb, q_raw, (const float*)nullptr, lamb, 1);
  hipLaunchKernelGGL(gemm_nt, ggf, gb, 0, stream, x, Wk, k_raw, (const float*)nullptr, lamb, 1);
  hipLaunchKernelGGL(gemm_bf16, ggb, gb, 0, stream, xb, wvb, v_mix, v1, lamb, 2);
  hipLaunchKernelGGL(kw_kernel, dim3(Bq * Tq), gb, 0, stream, x, Wkw, kwbuf);

  const int rows = Bq * Hq * Tq;
  hipLaunchKernelGGL(postproc, dim3(rows / 4), gb, 0, stream, q_raw, (float*)nullptr, q_bf, ln_q_w, ln_q_b, x_q, 1);
  hipLaunchKernelGGL(postproc, dim3(rows / 4), gb, 0, stream, k_raw, k_fin, k_bf, ln_k_w, ln_k_b, x_k, 1);
  hipLaunchKernelGGL(postproc, dim3(rows / 4), gb, 0, stream, v_mix, (float*)nullptr, v_bf,
                     (const float*)nullptr, (const float*)nullptr, x_v, 0);

  hipLaunchKernelGGL(state_evolve_kernel, dim3(Bq * Hq), dim3(1024), 0, stream,
                     k_fin, v_bf, kwbuf, dkn_bf, vst_bf, cnt_snap, ln_dk_w, ln_dk_b);

  hipLaunchKernelGGL(attn_mfma_kernel, dim3(Bq * Hq * 16), gb, 0, stream,
                     q_bf, k_bf, v_bf, dkn_bf, vst_bf, cnt_snap, ybuf, ftp, stp);

  hipLaunchKernelGGL(final_ln, dim3(Bq * Tq), gb, 0, stream, ybuf, ln_res_w, ln_res_b, ylnb_bf);
  hipLaunchKernelGGL(gemm_bf16, ggb, gb, 0, stream, ylnb_bf, wpb, (float*)d_out, residual, lamb, 3);
}

// Round 7
// 1377.668 us; speedup vs baseline: 3.0747x; 1.6372x over previous
//
#include <hip/hip_runtime.h>
#include <math.h>

#define Bq 4
#define Tq 2048
#define Cq 1024
#define Hq 16
#define Nq 64

typedef __attribute__((ext_vector_type(8))) short short8v;
typedef __attribute__((ext_vector_type(4))) float f32x4;

__device__ inline float waveSum(float v) {
#pragma unroll
  for (int o = 32; o; o >>= 1) v += __shfl_xor(v, o);
  return v;
}
__device__ inline unsigned short f2bf(float f) {
  unsigned u = __float_as_uint(f);
  unsigned r = (u + 0x7FFFu + ((u >> 16) & 1u)) >> 16;
  return (unsigned short)r;
}
__device__ inline float bf2f(unsigned short b) {
  return __uint_as_float(((unsigned)b) << 16);
}

__global__ __launch_bounds__(256) void f32_to_bf16_kernel(
    const float* __restrict__ src, unsigned short* __restrict__ dst, int n4)
{
  int i = blockIdx.x * 256 + threadIdx.x;
  if (i >= n4) return;
  float4 v = ((const float4*)src)[i];
  ushort4 o;
  o.x = f2bf(v.x); o.y = f2bf(v.y); o.z = f2bf(v.z); o.w = f2bf(v.w);
  ((ushort4*)dst)[i] = o;
}

// hi/lo split: hi = bf16(v), lo = bf16(v - hi). hi+lo carries ~16 mantissa bits.
__global__ __launch_bounds__(256) void f32_to_bf16_hilo_kernel(
    const float* __restrict__ src, unsigned short* __restrict__ hi,
    unsigned short* __restrict__ lo, int n4)
{
  int i = blockIdx.x * 256 + threadIdx.x;
  if (i >= n4) return;
  float4 v = ((const float4*)src)[i];
  ushort4 h, l;
  h.x = f2bf(v.x); l.x = f2bf(v.x - bf2f(h.x));
  h.y = f2bf(v.y); l.y = f2bf(v.y - bf2f(h.y));
  h.z = f2bf(v.z); l.z = f2bf(v.z - bf2f(h.z));
  h.w = f2bf(v.w); l.w = f2bf(v.w - bf2f(h.w));
  ((ushort4*)hi)[i] = h;
  ((ushort4*)lo)[i] = l;
}

// ---- bf16 MFMA GEMM (plain) ----
__global__ __launch_bounds__(256) void gemm_bf16(
    const unsigned short* __restrict__ A, const unsigned short* __restrict__ W,
    float* __restrict__ dst, const float* __restrict__ extra,
    const float* __restrict__ lamb_p, int mode)
{
  const int m0 = blockIdx.x * 128, n0 = blockIdx.y * 128;
  const int tid = threadIdx.x;
  const int w = tid >> 6, l = tid & 63;
  const int wr = w >> 1, wc = w & 1;
  const int lrow = l & 15;
  const int lk = (l >> 4) * 8;

  f32x4 acc[4][4];
#pragma unroll
  for (int i = 0; i < 4; ++i)
#pragma unroll
    for (int j = 0; j < 4; ++j) acc[i][j] = (f32x4){0.f, 0.f, 0.f, 0.f};

  const unsigned short* Ab = A + (((size_t)(m0 + wr * 64 + lrow)) << 10) + lk;
  const unsigned short* Wb = W + (((size_t)(n0 + wc * 64 + lrow)) << 10) + lk;

  for (int k0 = 0; k0 < 1024; k0 += 32) {
    short8v a[4], b[4];
#pragma unroll
    for (int i = 0; i < 4; ++i) a[i] = *(const short8v*)(Ab + (((size_t)i) << 14) + k0);
#pragma unroll
    for (int j = 0; j < 4; ++j) b[j] = *(const short8v*)(Wb + (((size_t)j) << 14) + k0);
#pragma unroll
    for (int i = 0; i < 4; ++i)
#pragma unroll
      for (int j = 0; j < 4; ++j)
        acc[i][j] = __builtin_amdgcn_mfma_f32_16x16x32_bf16(a[i], b[j], acc[i][j], 0, 0, 0);
  }

  const float lam = (mode == 2) ? lamb_p[0] : 0.0f;
#pragma unroll
  for (int i = 0; i < 4; ++i)
#pragma unroll
    for (int j = 0; j < 4; ++j)
#pragma unroll
      for (int rg = 0; rg < 4; ++rg) {
        int m = m0 + wr * 64 + i * 16 + (l >> 4) * 4 + rg;
        int n = n0 + wc * 64 + j * 16 + (l & 15);
        float v = acc[i][j][rg];
        if (mode == 3) {
          dst[(size_t)m * Cq + n] = v + extra[(size_t)m * Cq + n];
        } else {
          if (mode == 2) v = (1.0f - lam) * v + lam * extra[(size_t)m * Cq + n];
          int b = m >> 11, t = m & (Tq - 1);
          int h = n >> 6, nn = n & 63;
          dst[((((size_t)b * Hq + h) * Tq + t) << 6) | nn] = v;
        }
      }
}

// ---- split-precision bf16 MFMA GEMM (K path): acc = Ah*Wh + Ah*Wl + Al*Wh ----
// Stores transposed (B,H,T,N) f32.
__global__ __launch_bounds__(256) void gemm_bf16_split(
    const unsigned short* __restrict__ Ah, const unsigned short* __restrict__ Al,
    const unsigned short* __restrict__ Wh, const unsigned short* __restrict__ Wl,
    float* __restrict__ dst)
{
  const int m0 = blockIdx.x * 128, n0 = blockIdx.y * 128;
  const int tid = threadIdx.x;
  const int w = tid >> 6, l = tid & 63;
  const int wr = w >> 1, wc = w & 1;
  const int lrow = l & 15;
  const int lk = (l >> 4) * 8;

  f32x4 acc[4][4];
#pragma unroll
  for (int i = 0; i < 4; ++i)
#pragma unroll
    for (int j = 0; j < 4; ++j) acc[i][j] = (f32x4){0.f, 0.f, 0.f, 0.f};

  const size_t aoff = (((size_t)(m0 + wr * 64 + lrow)) << 10) + lk;
  const size_t woff = (((size_t)(n0 + wc * 64 + lrow)) << 10) + lk;
  const unsigned short* Ahb = Ah + aoff;
  const unsigned short* Alb = Al + aoff;
  const unsigned short* Whb = Wh + woff;
  const unsigned short* Wlb = Wl + woff;

  for (int k0 = 0; k0 < 1024; k0 += 32) {
    short8v ah[4], al[4], bh[4], bl[4];
#pragma unroll
    for (int i = 0; i < 4; ++i) {
      ah[i] = *(const short8v*)(Ahb + (((size_t)i) << 14) + k0);
      al[i] = *(const short8v*)(Alb + (((size_t)i) << 14) + k0);
    }
#pragma unroll
    for (int j = 0; j < 4; ++j) {
      bh[j] = *(const short8v*)(Whb + (((size_t)j) << 14) + k0);
      bl[j] = *(const short8v*)(Wlb + (((size_t)j) << 14) + k0);
    }
#pragma unroll
    for (int i = 0; i < 4; ++i)
#pragma unroll
      for (int j = 0; j < 4; ++j) {
        acc[i][j] = __builtin_amdgcn_mfma_f32_16x16x32_bf16(ah[i], bh[j], acc[i][j], 0, 0, 0);
        acc[i][j] = __builtin_amdgcn_mfma_f32_16x16x32_bf16(ah[i], bl[j], acc[i][j], 0, 0, 0);
        acc[i][j] = __builtin_amdgcn_mfma_f32_16x16x32_bf16(al[i], bh[j], acc[i][j], 0, 0, 0);
      }
  }

#pragma unroll
  for (int i = 0; i < 4; ++i)
#pragma unroll
    for (int j = 0; j < 4; ++j)
#pragma unroll
      for (int rg = 0; rg < 4; ++rg) {
        int m = m0 + wr * 64 + i * 16 + (l >> 4) * 4 + rg;
        int n = n0 + wc * 64 + j * 16 + (l & 15);
        int b = m >> 11, t = m & (Tq - 1);
        int h = n >> 6, nn = n & 63;
        dst[((((size_t)b * Hq + h) * Tq + t) << 6) | nn] = acc[i][j][rg];
      }
}

// LN (optional) + token-shift + RoPE (optional). src in (B,H,T,N).
__global__ __launch_bounds__(256) void postproc(
    const float* __restrict__ src, float* __restrict__ dst,
    unsigned short* __restrict__ dst_bf,
    const float* __restrict__ lnw, const float* __restrict__ lnb,
    const float* __restrict__ xs_p, int doLNRope)
{
  const int w = threadIdx.x >> 6, lane = threadIdx.x & 63;
  const int row = blockIdx.x * 4 + w;
  const int t = row & (Tq - 1);
  const int h = (row >> 11) & (Hq - 1);
  const size_t base = (size_t)row << 6;
  const size_t pbase = (t > 0) ? base - 64 : base;
  float cur = src[base + lane];
  float prv = src[pbase + lane];
  if (doLNRope) {
    const float lw = lnw[lane], lb = lnb[lane];
    {
      float m = waveSum(cur) * (1.0f / 64.0f);
      float d = cur - m;
      float var = waveSum(d * d) * (1.0f / 64.0f);
      cur = d * rsqrtf(var + 1e-5f) * lw + lb;
    }
    {
      float m = waveSum(prv) * (1.0f / 64.0f);
      float d = prv - m;
      float var = waveSum(d * d) * (1.0f / 64.0f);
      prv = d * rsqrtf(var + 1e-5f) * lw + lb;
    }
  }
  const float xv = xs_p[h * 64 + lane];
  float val = cur + xv * (prv - cur);
  if (doLNRope) {
    float partner = __shfl_xor(val, 1);
    if (lane < 32) {
      int i = lane >> 1;
      float freq = (float)exp((double)i * (-log(10000.0) / 15.0));
      float th = (float)t * freq;
      float c = cosf(th), s = sinf(th);
      val = c * val + ((lane & 1) ? -s : s) * partner;
    }
  }
  if (dst) dst[base + lane] = val;
  if (dst_bf) dst_bf[base + lane] = f2bf(val);
}

__global__ __launch_bounds__(256) void kw_kernel(
    const float* __restrict__ x, const float* __restrict__ Wkw, float* __restrict__ out)
{
  const int bt = blockIdx.x;
  const int tid = threadIdx.x, w = tid >> 6, lane = tid & 63;
  __shared__ float xs[Cq];
  for (int i = tid; i < Cq; i += 256) xs[i] = x[(size_t)bt * Cq + i];
  __syncthreads();
  const int b = bt >> 11, t = bt & (Tq - 1);
  for (int h = w; h < Hq; h += 4) {
    float acc = 0.0f;
    for (int i = lane; i < Cq; i += 64) acc += xs[i] * Wkw[h * Cq + i];
    acc = waveSum(acc);
    if (lane == 0) out[((size_t)(b * Hq + h)) * Tq + t] = 1.0f / (1.0f + expf(-acc));
  }
}

// Phase A: state evolution, 64 blocks x 1024 threads. State in registers.
// sim uses rank-1 decomposition for dims<32 (ck0[rc][d<32] = a_rc*lnw[d]+lnb[d]):
//   sim[rc][s] = a_rc*P[s] + Q[s] + sum_{d>=32} ck0[rc][d]*dkn[s][d]
// k-major LDS (stride 260), linear addressing, conflict-free.
__global__ __launch_bounds__(1024, 4) void state_evolve_kernel(
    const float* __restrict__ kf, const unsigned short* __restrict__ v_bf,
    const float* __restrict__ kwp,
    unsigned short* __restrict__ dkn_bf, unsigned short* __restrict__ vst_bf,
    float* __restrict__ cnt_snap,
    const float* __restrict__ lnw, const float* __restrict__ lnb)
{
  const int bh = blockIdx.x;
  const int tid = threadIdx.x;
  const int s = tid >> 2, qd = tid & 3;
  const int db = qd * 16;
  const size_t seq = (size_t)Tq * Nq;
  const float* kb_ = kf + (size_t)bh * seq;
  const unsigned short* vb_ = v_bf + (size_t)bh * seq;
  const float* kwb = kwp + (size_t)bh * Tq;

  __shared__ float dknT[32 * 260];          // [d-32][slot], k-major
  __shared__ float ck0T[32 * 260];          // [d-32][rc], k-major
  __shared__ unsigned short VRow[256 * 72]; // bf16 V window rows
  __shared__ float Ps[256], Qs[256], aS[256], kwS[256];
  __shared__ float lwS[64], lbS[64];
  __shared__ int best[256];

  if (tid < 64) { lwS[tid] = lnw[tid]; lbS[tid] = lnb[tid]; }

  float dkReg[16], dvReg[16];
#pragma unroll
  for (int i = 0; i < 16; ++i) { dkReg[i] = 0.f; dvReg[i] = 0.f; }
  float cnt = 0.f;
  __syncthreads();

  for (int c = 0; c < 8; ++c) {
    const int e = c * 256 + 256;
    const int bb = (e - 512 > 0) ? (e - 512) : 0;

    // ---- A: LN(d_k) -> snapshot + dknT + P/Q; unit v_state -> snapshot; cnt
    {
      float sum = 0.f;
#pragma unroll
      for (int i = 0; i < 16; ++i) sum += dkReg[i];
      sum += __shfl_xor(sum, 1); sum += __shfl_xor(sum, 2);
      const float mean = sum * (1.0f / 64.0f);
      float sq = 0.f;
#pragma unroll
      for (int i = 0; i < 16; ++i) { float d = dkReg[i] - mean; sq += d * d; }
      sq += __shfl_xor(sq, 1); sq += __shfl_xor(sq, 2);
      const float rs = rsqrtf(sq * (1.0f / 64.0f) + 1e-5f);
      float kn[16];
#pragma unroll
      for (int i = 0; i < 16; ++i)
        kn[i] = (dkReg[i] - mean) * rs * lwS[db + i] + lbS[db + i];
      unsigned int pk[8];
#pragma unroll
      for (int i2 = 0; i2 < 8; ++i2)
        pk[i2] = (unsigned)f2bf(kn[2 * i2]) | ((unsigned)f2bf(kn[2 * i2 + 1]) << 16);
      unsigned short* kd = dkn_bf + (((size_t)bh * 8 + c) << 14) + s * 64 + db;
      *(uint4*)kd = make_uint4(pk[0], pk[1], pk[2], pk[3]);
      *(uint4*)(kd + 8) = make_uint4(pk[4], pk[5], pk[6], pk[7]);

      if (c < 7) {
        if (qd >= 2) {
#pragma unroll
          for (int i = 0; i < 16; ++i) dknT[(db - 32 + i) * 260 + s] = kn[i];
        } else {
          float pp = 0.f, qq = 0.f;
#pragma unroll
          for (int i = 0; i < 16; ++i) {
            pp += kn[i] * lwS[db + i];
            qq += kn[i] * lbS[db + i];
          }
          pp += __shfl_xor(pp, 1);
          qq += __shfl_xor(qq, 1);
          if (qd == 0) { Ps[s] = pp; Qs[s] = qq; }
        }
      }

      float sqv = 0.f;
#pragma unroll
      for (int i = 0; i < 16; ++i) sqv += dvReg[i] * dvReg[i];
      sqv += __shfl_xor(sqv, 1); sqv += __shfl_xor(sqv, 2);
      const float inrm = 1.0f / fmaxf(sqrtf(sqv), 1e-12f);
#pragma unroll
      for (int i2 = 0; i2 < 8; ++i2)
        pk[i2] = (unsigned)f2bf(dvReg[2 * i2] * inrm) |
                 ((unsigned)f2bf(dvReg[2 * i2 + 1] * inrm) << 16);
      unsigned short* vd = vst_bf + (((size_t)bh * 8 + c) << 14) + s * 64 + db;
      *(uint4*)vd = make_uint4(pk[0], pk[1], pk[2], pk[3]);
      *(uint4*)(vd + 8) = make_uint4(pk[4], pk[5], pk[6], pk[7]);
      if (qd == 0) cnt_snap[((size_t)bh * 8 + c) * 256 + s] = cnt;
    }

    if (c == 7) break;

    // ---- B: ck0 LN (-> ck0T dims>=32, aS, kwS) + V window stage (bf16)
    {
      float kv[16];
      if (qd >= 2) {
        const float* krow = kb_ + (size_t)(bb + s) * 64 + db;
#pragma unroll
        for (int i = 0; i < 16; i += 4) {
          float4 t4 = *(const float4*)(krow + i);
          kv[i] = t4.x; kv[i + 1] = t4.y; kv[i + 2] = t4.z; kv[i + 3] = t4.w;
        }
      } else {
#pragma unroll
        for (int i = 0; i < 16; ++i) kv[i] = 0.f;
      }
      float sum = 0.f;
#pragma unroll
      for (int i = 0; i < 16; ++i) sum += kv[i];
      sum += __shfl_xor(sum, 1); sum += __shfl_xor(sum, 2);
      const float mean = sum * (1.0f / 64.0f);
      float sq = 0.f;
#pragma unroll
      for (int i = 0; i < 16; ++i) { float d = kv[i] - mean; sq += d * d; }
      sq += __shfl_xor(sq, 1); sq += __shfl_xor(sq, 2);
      const float rs = rsqrtf(sq * (1.0f / 64.0f) + 1e-5f);
      if (qd >= 2) {
#pragma unroll
        for (int i = 0; i < 16; ++i)
          ck0T[(db - 32 + i) * 260 + s] =
              (kv[i] - mean) * rs * lwS[db + i] + lbS[db + i];
      }
      if (qd == 0) {
        aS[s] = (0.0f - mean) * rs;
        kwS[s] = kwb[bb + s];
      }
      // V stage: row s, 16 bf16 at db (byte addr 144*s + 2*db, 16B aligned)
      const unsigned short* vsrc = vb_ + (size_t)(bb + s) * 64 + db;
      *(uint4*)&VRow[s * 72 + db] = *(const uint4*)vsrc;
      *(uint4*)&VRow[s * 72 + db + 8] = *(const uint4*)(vsrc + 8);
    }
    __syncthreads();

    // ---- C: sim + fused argmax
    {
      const int tx = tid & 31, ty = tid >> 5;
#pragma unroll
      for (int pass = 0; pass < 2; ++pass) {
        const int rc0 = pass * 128 + ty * 4;
        float a4[4];
#pragma unroll
        for (int i = 0; i < 4; ++i) a4[i] = aS[rc0 + i];
        float acc[4][8];
#pragma unroll
        for (int j = 0; j < 8; ++j) {
          const float pj = Ps[tx + 32 * j], qj = Qs[tx + 32 * j];
#pragma unroll
          for (int i = 0; i < 4; ++i) acc[i][j] = a4[i] * pj + qj;
        }
#pragma unroll 8
        for (int k = 0; k < 32; ++k) {
          f32x4 av = *(const f32x4*)&ck0T[k * 260 + rc0];
          float bv[8];
#pragma unroll
          for (int j = 0; j < 8; ++j) bv[j] = dknT[k * 260 + tx + 32 * j];
#pragma unroll
          for (int i = 0; i < 4; ++i)
#pragma unroll
            for (int j = 0; j < 8; ++j) acc[i][j] += av[i] * bv[j];
        }
#pragma unroll
        for (int i = 0; i < 4; ++i) {
          float bvv = -3.0e38f;
          int bi = 1 << 30;
#pragma unroll
          for (int j = 0; j < 8; ++j) {
            int s2 = tx + 32 * j;
            float v = acc[i][j];
            if (s2 == 0) v = -1.0e30f;  // SINK
            if (v > bvv || (v == bvv && s2 < bi)) { bvv = v; bi = s2; }
          }
#pragma unroll
          for (int o = 16; o; o >>= 1) {
            float ov = __shfl_xor(bvv, o);
            int oi = __shfl_xor(bi, o);
            if (ov > bvv || (ov == bvv && oi < bi)) { bvv = ov; bi = oi; }
          }
          if (tx == 0) best[rc0 + i] = bi;
        }
      }
    }
    __syncthreads();

    // ---- D: ownership scatter into registers
    {
      int cadd = 0;
      for (int rc = 0; rc < 256; ++rc) {
        if (best[rc] == s) {
          const float kwv = kwS[rc];
          if (qd < 2) {
            const float a = aS[rc];
#pragma unroll
            for (int i = 0; i < 16; ++i)
              dkReg[i] += (a * lwS[db + i] + lbS[db + i]) * kwv;
          } else {
#pragma unroll
            for (int i = 0; i < 16; ++i)
              dkReg[i] += ck0T[(db - 32 + i) * 260 + rc] * kwv;
          }
          const uint4 u0 = *(const uint4*)&VRow[rc * 72 + db];
          const uint4 u1 = *(const uint4*)&VRow[rc * 72 + db + 8];
          const unsigned uu[8] = {u0.x, u0.y, u0.z, u0.w, u1.x, u1.y, u1.z, u1.w};
#pragma unroll
          for (int i2 = 0; i2 < 8; ++i2) {
            dvReg[2 * i2] += __uint_as_float((uu[i2] & 0xFFFFu) << 16) * kwv;
            dvReg[2 * i2 + 1] += __uint_as_float(uu[i2] & 0xFFFF0000u) * kwv;
          }
          ++cadd;
        }
      }
      cnt += (float)cadd;
    }
    __syncthreads();
  }
}

// Phase B: MFMA flash attention. Grid 1024 = (bh, c, half); 256 thr, 4 waves x 32 rows.
__global__ __launch_bounds__(256, 2) void attn_mfma_kernel(
    const unsigned short* __restrict__ q_bf, const unsigned short* __restrict__ k_bf,
    const unsigned short* __restrict__ v_bf,
    const unsigned short* __restrict__ dkn_bf, const unsigned short* __restrict__ vst_bf,
    const float* __restrict__ cnt_snap, float* __restrict__ y,
    const float* __restrict__ ftp, const float* __restrict__ stp)
{
  const int blk = blockIdx.x;
  const int bh = blk >> 4;
  const int c = (blk >> 1) & 7;
  const int half = blk & 1;
  const int h = bh & (Hq - 1);
  const int tid = threadIdx.x;
  const int w = tid >> 6, l = tid & 63;
  const int g = l >> 4, n = l & 15;
  const int rows0 = c * 256 + half * 128 + w * 32;
  const int e = c * 256 + 256;
  const int bb = (e - 512 > 0) ? (e - 512) : 0;
  const int nwt = (e - bb) >> 6;  // 4 or 8
  const float stsc = stp[h] * 0.125f, ftsc = ftp[h] * 0.125f;
  const size_t seq = (size_t)Tq * Nq;

  __shared__ unsigned short Ks[64 * 72];
  __shared__ unsigned short VTs[64 * 72];
  __shared__ unsigned short Ps[4][32 * 72];
  __shared__ float wts[64];

  short8v qf[2][2];
#pragma unroll
  for (int mt = 0; mt < 2; ++mt)
#pragma unroll
    for (int kh = 0; kh < 2; ++kh)
      qf[mt][kh] = *(const short8v*)(q_bf + (size_t)bh * seq +
                                     (size_t)(rows0 + mt * 16 + n) * 64 + kh * 32 + g * 8);

  f32x4 oacc[2][4];
#pragma unroll
  for (int mt = 0; mt < 2; ++mt)
#pragma unroll
    for (int dt = 0; dt < 4; ++dt) oacc[mt][dt] = (f32x4){0.f, 0.f, 0.f, 0.f};
  float rowM[2][4], rowL[2][4];
#pragma unroll
  for (int mt = 0; mt < 2; ++mt)
#pragma unroll
    for (int r = 0; r < 4; ++r) { rowM[mt][r] = -1.0e30f; rowL[mt][r] = 0.f; }

  const int nkt = 4 + nwt;
  for (int kt = 0; kt < nkt; ++kt) {
    const bool isState = kt < 4;
    const int t0 = isState ? kt * 64 : bb + (kt - 4) * 64;
    const unsigned short* ksrc = isState
        ? dkn_bf + (((size_t)bh * 8 + c) << 14) + (size_t)t0 * 64
        : k_bf + (size_t)bh * seq + (size_t)t0 * 64;
    const unsigned short* vsrc = isState
        ? vst_bf + (((size_t)bh * 8 + c) << 14) + (size_t)t0 * 64
        : v_bf + (size_t)bh * seq + (size_t)t0 * 64;

    __syncthreads();
    {
      const int row = tid >> 2, q4 = tid & 3;
      const unsigned short* src = ksrc + row * 64 + q4 * 16;
      *(uint4*)&Ks[row * 72 + q4 * 16] = *(const uint4*)src;
      *(uint4*)&Ks[row * 72 + q4 * 16 + 8] = *(const uint4*)(src + 8);
      const unsigned short* vs = vsrc + row * 64 + q4 * 16;
#pragma unroll
      for (int i = 0; i < 16; ++i) VTs[(q4 * 16 + i) * 72 + row] = vs[i];
      if (tid < 64)
        wts[tid] = isState ? cnt_snap[((size_t)bh * 8 + c) * 256 + kt * 64 + tid] : 1.0f;
    }
    __syncthreads();

    f32x4 sacc[2][4];
#pragma unroll
    for (int mt = 0; mt < 2; ++mt)
#pragma unroll
      for (int nt = 0; nt < 4; ++nt) sacc[mt][nt] = (f32x4){0.f, 0.f, 0.f, 0.f};
#pragma unroll
    for (int nt = 0; nt < 4; ++nt) {
      short8v kf0 = *(const short8v*)&Ks[(nt * 16 + n) * 72 + g * 8];
      short8v kf1 = *(const short8v*)&Ks[(nt * 16 + n) * 72 + 32 + g * 8];
#pragma unroll
      for (int mt = 0; mt < 2; ++mt) {
        sacc[mt][nt] = __builtin_amdgcn_mfma_f32_16x16x32_bf16(qf[mt][0], kf0, sacc[mt][nt], 0, 0, 0);
        sacc[mt][nt] = __builtin_amdgcn_mfma_f32_16x16x32_bf16(qf[mt][1], kf1, sacc[mt][nt], 0, 0, 0);
      }
    }

    const float scale = isState ? stsc : ftsc;
    float wt_n[4];
#pragma unroll
    for (int nt = 0; nt < 4; ++nt) wt_n[nt] = wts[nt * 16 + n];

#pragma unroll
    for (int mt = 0; mt < 2; ++mt) {
#pragma unroll
      for (int r = 0; r < 4; ++r) {
        float sv[4];
#pragma unroll
        for (int nt = 0; nt < 4; ++nt) {
          float s = sacc[mt][nt][r] * scale;
          if (!isState) {
            int qi = rows0 + mt * 16 + g * 4 + r;
            int kj = t0 + nt * 16 + n;
            if (kj > qi) s = -1.0e30f;
          }
          sv[nt] = s;
        }
        float tmax = fmaxf(fmaxf(sv[0], sv[1]), fmaxf(sv[2], sv[3]));
        tmax = fmaxf(tmax, __shfl_xor(tmax, 1));
        tmax = fmaxf(tmax, __shfl_xor(tmax, 2));
        tmax = fmaxf(tmax, __shfl_xor(tmax, 4));
        tmax = fmaxf(tmax, __shfl_xor(tmax, 8));
        const float Mold = rowM[mt][r];
        const float Mnew = fmaxf(Mold, tmax);
        const float al = __expf(Mold - Mnew);
        rowM[mt][r] = Mnew;
        float p[4], ts = 0.f;
#pragma unroll
        for (int nt = 0; nt < 4; ++nt) { p[nt] = __expf(sv[nt] - Mnew); ts += p[nt]; }
        ts += __shfl_xor(ts, 1);
        ts += __shfl_xor(ts, 2);
        ts += __shfl_xor(ts, 4);
        ts += __shfl_xor(ts, 8);
        rowL[mt][r] = rowL[mt][r] * al + ts;
#pragma unroll
        for (int dt = 0; dt < 4; ++dt) oacc[mt][dt][r] *= al;
        const int prow = (mt * 16 + g * 4 + r) * 72;
#pragma unroll
        for (int nt = 0; nt < 4; ++nt)
          Ps[w][prow + nt * 16 + n] = f2bf(p[nt] * wt_n[nt]);
      }
    }

    short8v pf[2][2];
#pragma unroll
    for (int mt = 0; mt < 2; ++mt)
#pragma unroll
      for (int jh = 0; jh < 2; ++jh)
        pf[mt][jh] = *(const short8v*)&Ps[w][(mt * 16 + n) * 72 + jh * 32 + g * 8];
#pragma unroll
    for (int dt = 0; dt < 4; ++dt) {
      short8v vf0 = *(const short8v*)&VTs[(dt * 16 + n) * 72 + g * 8];
      short8v vf1 = *(const short8v*)&VTs[(dt * 16 + n) * 72 + 32 + g * 8];
#pragma unroll
      for (int mt = 0; mt < 2; ++mt) {
        oacc[mt][dt] = __builtin_amdgcn_mfma_f32_16x16x32_bf16(pf[mt][0], vf0, oacc[mt][dt], 0, 0, 0);
        oacc[mt][dt] = __builtin_amdgcn_mfma_f32_16x16x32_bf16(pf[mt][1], vf1, oacc[mt][dt], 0, 0, 0);
      }
    }
  }

#pragma unroll
  for (int mt = 0; mt < 2; ++mt) {
#pragma unroll
    for (int r = 0; r < 4; ++r) {
      const float inv = 1.0f / rowL[mt][r];
      const int row = rows0 + mt * 16 + g * 4 + r;
#pragma unroll
      for (int dt = 0; dt < 4; ++dt)
        y[(size_t)bh * seq + (size_t)row * 64 + dt * 16 + n] = oacc[mt][dt][r] * inv;
    }
  }
}

// LN over C=1024 per (b,t); gathers from (B,H,T,N), writes bf16 (B,T,C)
__global__ __launch_bounds__(256) void final_ln(
    const float* __restrict__ y, const float* __restrict__ lnw,
    const float* __restrict__ lnb, unsigned short* __restrict__ dst)
{
  const int bt = blockIdx.x;
  const int b = bt >> 11, t = bt & (Tq - 1);
  const int tid = threadIdx.x, w = tid >> 6, lane = tid & 63;
  __shared__ float red[8];
  float v[4];
  float s = 0.0f;
#pragma unroll
  for (int i = 0; i < 4; ++i) {
    int c = tid + (i << 8);
    int h = c >> 6, n = c & 63;
    v[i] = y[((((size_t)b * Hq + h) * Tq + t) << 6) + n];
    s += v[i];
  }
  s = waveSum(s);
  if (lane == 0) red[w] = s;
  __syncthreads();
  const float mean = (red[0] + red[1] + red[2] + red[3]) * (1.0f / 1024.0f);
  float s2 = 0.0f;
#pragma unroll
  for (int i = 0; i < 4; ++i) { float d = v[i] - mean; s2 += d * d; }
  s2 = waveSum(s2);
  if (lane == 0) red[4 + w] = s2;
  __syncthreads();
  const float var = (red[4] + red[5] + red[6] + red[7]) * (1.0f / 1024.0f);
  const float rs = rsqrtf(var + 1e-5f);
#pragma unroll
  for (int i = 0; i < 4; ++i) {
    int c = tid + (i << 8);
    dst[(size_t)bt * Cq + c] = f2bf((v[i] - mean) * rs * lnw[c] + lnb[c]);
  }
}

extern "C" void kernel_launch(void* const* d_in, const int* in_sizes, int n_in,
                              void* d_out, int out_size, void* d_ws, size_t ws_size,
                              hipStream_t stream)
{
  (void)in_sizes; (void)n_in; (void)out_size; (void)ws_size;
  const float* residual = (const float*)d_in[0];
  const float* x        = (const float*)d_in[1];
  const float* v1       = (const float*)d_in[2];
  const float* Wq       = (const float*)d_in[6];
  const float* Wk       = (const float*)d_in[7];
  const float* Wv       = (const float*)d_in[8];
  const float* Wproj    = (const float*)d_in[9];
  const float* Wkw      = (const float*)d_in[10];
  const float* x_q      = (const float*)d_in[11];
  const float* x_k      = (const float*)d_in[12];
  const float* x_v      = (const float*)d_in[13];
  const float* lamb     = (const float*)d_in[14];
  const float* ln_q_w   = (const float*)d_in[15];
  const float* ln_q_b   = (const float*)d_in[16];
  const float* ln_k_w   = (const float*)d_in[17];
  const float* ln_k_b   = (const float*)d_in[18];
  const float* ln_dk_w  = (const float*)d_in[19];
  const float* ln_dk_b  = (const float*)d_in[20];
  const float* ln_res_w = (const float*)d_in[21];
  const float* ln_res_b = (const float*)d_in[22];
  const float* ftp      = (const float*)d_in[23];
  const float* stp      = (const float*)d_in[24];

  float* ws = (float*)d_ws;
  const size_t SZ = (size_t)Bq * Hq * Tq * Nq;  // 8388608
  // region A: q_raw (f32 gemm out) -> ybuf (attn out)
  float* q_raw = ws;
  float* ybuf  = ws;
  // region B: k_raw -> {vst_bf, cnt_snap}
  float* k_raw = ws + SZ;
  unsigned short* vst_bf = (unsigned short*)(ws + SZ);
  float* cnt_snap = ws + SZ + SZ / 2;
  // region C: v_mix -> ylnb_bf
  float* v_mix = ws + 2 * SZ;
  unsigned short* ylnb_bf = (unsigned short*)(ws + 2 * SZ);
  // region D: k_fin (f32, state path)
  float* k_fin = ws + 3 * SZ;
  // region E: [pre-postproc] x_lo | wk_hi | wk_lo ; [post] q_bf | k_bf
  unsigned short* q_bf = (unsigned short*)(ws + 4 * SZ);
  unsigned short* x_lo = q_bf;                       // dead before postproc-q
  unsigned short* k_bf = q_bf + SZ;
  unsigned short* wk_hi = k_bf;                      // dead before postproc-k
  unsigned short* wk_lo = wk_hi + (1u << 20);
  // region F: v_bf | xb(x_hi) -> dkn_bf
  unsigned short* v_bf = (unsigned short*)(ws + 5 * SZ);
  unsigned short* xb   = v_bf + SZ;
  unsigned short* dkn_bf = xb;                       // xb dead after gemms
  // region G: weights bf16 + kwbuf
  unsigned short* wqb = (unsigned short*)(ws + 6 * SZ);
  unsigned short* wvb = wqb + (1u << 20);
  unsigned short* wpb = wvb + (1u << 20);
  float* kwbuf = ws + 6 * SZ + ((3u << 20) >> 1);

  dim3 gb(256);
  dim3 ggb(64, 8);

  hipLaunchKernelGGL(f32_to_bf16_hilo_kernel, dim3((int)(SZ / 4 / 256)), gb, 0, stream,
                     x, xb, x_lo, (int)(SZ / 4));
  hipLaunchKernelGGL(f32_to_bf16_hilo_kernel, dim3(1024), gb, 0, stream,
                     Wk, wk_hi, wk_lo, 262144);
  hipLaunchKernelGGL(f32_to_bf16_kernel, dim3(1024), gb, 0, stream, Wq, wqb, 262144);
  hipLaunchKernelGGL(f32_to_bf16_kernel, dim3(1024), gb, 0, stream, Wv, wvb, 262144);
  hipLaunchKernelGGL(f32_to_bf16_kernel, dim3(1024), gb, 0, stream, Wproj, wpb, 262144);

  hipLaunchKernelGGL(gemm_bf16, ggb, gb, 0, stream, xb, wqb, q_raw, (const float*)nullptr, lamb, 1);
  hipLaunchKernelGGL(gemm_bf16_split, ggb, gb, 0, stream, xb, x_lo, wk_hi, wk_lo, k_raw);
  hipLaunchKernelGGL(gemm_bf16, ggb, gb, 0, stream, xb, wvb, v_mix, v1, lamb, 2);
  hipLaunchKernelGGL(kw_kernel, dim3(Bq * Tq), gb, 0, stream, x, Wkw, kwbuf);

  const int rows = Bq * Hq * Tq;
  hipLaunchKernelGGL(postproc, dim3(rows / 4), gb, 0, stream, q_raw, (float*)nullptr, q_bf, ln_q_w, ln_q_b, x_q, 1);
  hipLaunchKernelGGL(postproc, dim3(rows / 4), gb, 0, stream, k_raw, k_fin, k_bf, ln_k_w, ln_k_b, x_k, 1);
  hipLaunchKernelGGL(postproc, dim3(rows / 4), gb, 0, stream, v_mix, (float*)nullptr, v_bf,
                     (const float*)nullptr, (const float*)nullptr, x_v, 0);

  hipLaunchKernelGGL(state_evolve_kernel, dim3(Bq * Hq), dim3(1024), 0, stream,
                     k_fin, v_bf, kwbuf, dkn_bf, vst_bf, cnt_snap, ln_dk_w, ln_dk_b);

  hipLaunchKernelGGL(attn_mfma_kernel, dim3(Bq * Hq * 16), gb, 0, stream,
                     q_bf, k_bf, v_bf, dkn_bf, vst_bf, cnt_snap, ybuf, ftp, stp);

  hipLaunchKernelGGL(final_ln, dim3(Bq * Tq), gb, 0, stream, ybuf, ln_res_w, ln_res_b, ylnb_bf);
  hipLaunchKernelGGL(gemm_bf16, ggb, gb, 0, stream, ylnb_bf, wpb, (float*)d_out, residual, lamb, 3);
}